// Round 5
// baseline (403.291 us; speedup 1.0000x reference)
//
#include <hip/hip_runtime.h>

typedef __attribute__((ext_vector_type(8))) __bf16 bfx8;
typedef __attribute__((ext_vector_type(4))) float f32x4;

__device__ __forceinline__ float s2f(unsigned short s) {
  return __uint_as_float((unsigned int)s << 16);
}
// round-half-up bf16 convert (2 VALU ops; tie-only difference vs RNE)
__device__ __forceinline__ unsigned short f2s(float f) {
  return (unsigned short)((__float_as_uint(f) + 0x8000u) >> 16);
}

// ---------------------------------------------------------------------------
// Async MFMA GEMM core (global_load_lds staging, XOR-swizzled; R5-verified:
// SQ_LDS_BANK_CONFLICT == 0). Both operands [row][k] k-contiguous.
// D[m][n] = sum_k Ag[m][k]*Bg[n][k]. 256 thr = 4 waves 2x2.
// ---------------------------------------------------------------------------
template<int BM, int BN, int BK>
__device__ __forceinline__ void gemm_core_async(
    const unsigned short* __restrict__ Ag, int lda,
    const unsigned short* __restrict__ Bg, int ldb, int K,
    unsigned short* As, unsigned short* Bs, f32x4* acc)
{
  static_assert(BK == 64, "BK must be 64 (128B rows)");
  constexpr int WM = BM / 2, WN = BN / 2;
  constexpr int MT = WM / 16, NT = WN / 16;
  constexpr int SA = BM / 8, SB = BN / 8;   // 1024B segments per tile
  const int tid = threadIdx.x;
  const int lane = tid & 63, wave = tid >> 6;
  const int lr = lane & 15, quad = lane >> 4;
  const int sw = lr & 7;
  const int rl = lane >> 3;                  // row within segment (0..7)
  const int vg = (lane & 7) ^ rl;            // swizzled global vec index
  const int wm = (wave >> 1) * WM, wn = (wave & 1) * WN;

  for (int k0 = 0; k0 < K; k0 += BK) {
#pragma unroll
    for (int s = wave; s < SA; s += 4) {
      const unsigned short* g = Ag + (size_t)(s * 8 + rl) * lda + k0 + vg * 8;
      __builtin_amdgcn_global_load_lds(
          (__attribute__((address_space(1))) void*)g,
          (__attribute__((address_space(3))) void*)(As + s * 512), 16, 0, 0);
    }
#pragma unroll
    for (int s = wave; s < SB; s += 4) {
      const unsigned short* g = Bg + (size_t)(s * 8 + rl) * ldb + k0 + vg * 8;
      __builtin_amdgcn_global_load_lds(
          (__attribute__((address_space(1))) void*)g,
          (__attribute__((address_space(3))) void*)(Bs + s * 512), 16, 0, 0);
    }
    __syncthreads();
#pragma unroll
    for (int kk = 0; kk < BK; kk += 32) {
      const int kv = kk >> 3;                // 0 or 4
      bfx8 af[MT], bfr[NT];
#pragma unroll
      for (int i = 0; i < MT; ++i)
        af[i] = *(const bfx8*)(As + (wm + i * 16 + lr) * BK
                               + (((quad + kv) ^ sw) << 3));
#pragma unroll
      for (int j = 0; j < NT; ++j)
        bfr[j] = *(const bfx8*)(Bs + (wn + j * 16 + lr) * BK
                                + (((quad + kv) ^ sw) << 3));
#pragma unroll
      for (int i = 0; i < MT; ++i)
#pragma unroll
        for (int j = 0; j < NT; ++j)
          acc[i * NT + j] = __builtin_amdgcn_mfma_f32_16x16x32_bf16(
              af[i], bfr[j], acc[i * NT + j], 0, 0, 0);
    }
    __syncthreads();
  }
}

// ---------------------------------------------------------------------------
// k_pre: fused x transpose (fp32 [4][512][4096] -> bf16 x_t [4][4096][512],
// blocks 0..2047) and weight converts (blocks 2048..3071).
// ---------------------------------------------------------------------------
__global__ __launch_bounds__(256) void k_pre(
    const float* __restrict__ x, unsigned short* __restrict__ xt,
    const float* __restrict__ wq, const float* __restrict__ wk,
    const float* __restrict__ wv, const float* __restrict__ wW,
    unsigned short* __restrict__ wqk, unsigned short* __restrict__ wvb,
    unsigned short* __restrict__ wWb)
{
  const int bid = blockIdx.x, tid = threadIdx.x;
  if (bid < 2048) {
    __shared__ float t[64][65];
    const int b = bid >> 9, c0 = ((bid >> 6) & 7) * 64, n0 = (bid & 63) * 64;
    const float* xb = x + ((size_t)b << 21);
    const int hi = tid >> 6, lo = tid & 63;
#pragma unroll
    for (int p = 0; p < 16; ++p)
      t[hi + p * 4][lo] = xb[(size_t)(c0 + hi + p * 4) * 4096 + n0 + lo];
    __syncthreads();
    unsigned short* xtb = xt + ((size_t)b << 21);
#pragma unroll
    for (int p = 0; p < 16; ++p)
      xtb[(size_t)(n0 + hi + p * 4) * 512 + c0 + lo] = f2s(t[lo][hi + p * 4]);
  } else {
    int i = (bid - 2048) * 256 + tid;              // i < 262144
    wqk[i] = f2s(i < 131072 ? wq[i] : wk[i - 131072]);
    if (i < 131072) { wvb[i] = f2s(wv[i]); wWb[i] = f2s(wW[i]); }
  }
}

// ---------------------------------------------------------------------------
// k_qkv: fused QK GEMM (+fp32 BN stats partials in epilogue) and V GEMM.
// ---------------------------------------------------------------------------
__global__ __launch_bounds__(256) void k_qkv(
    const unsigned short* __restrict__ xt, const unsigned short* __restrict__ wqk,
    const unsigned short* __restrict__ wvb, const float* __restrict__ bv,
    unsigned short* __restrict__ zt, unsigned short* __restrict__ v,
    float* __restrict__ stat)
{
  __shared__ __align__(16) unsigned short As[128 * 64], Bs[128 * 64];
  f32x4 acc[16] = {};
  const int b = blockIdx.z, n0 = blockIdx.x * 128, t = blockIdx.y;
  const int lane = threadIdx.x & 63, wave = threadIdx.x >> 6;
  const int lr = lane & 15, quad = lane >> 4;
  const int wm = (wave >> 1) * 64, wn = (wave & 1) * 64;

  if (t < 4) {
    const int o0 = t * 128;
    gemm_core_async<128, 128, 64>(xt + ((size_t)b * 4096 + n0) * 512, 512,
                                  wqk + (size_t)o0 * 512, 512, 512, As, Bs, acc);
    float s[4] = {}, ss[4] = {};
#pragma unroll
    for (int i = 0; i < 4; ++i)
#pragma unroll
      for (int j = 0; j < 4; ++j)
#pragma unroll
        for (int r = 0; r < 4; ++r) {
          float a = acc[i * 4 + j][r];
          int row = wm + i * 16 + quad * 4 + r, col = wn + j * 16 + lr;
          zt[((size_t)b * 4096 + n0 + row) * 512 + o0 + col] = f2s(a);
          s[j] += a; ss[j] += a * a;
        }
#pragma unroll
    for (int j = 0; j < 4; ++j) {
      s[j]  += __shfl_down(s[j], 32, 64);  s[j]  += __shfl_down(s[j], 16, 64);
      ss[j] += __shfl_down(ss[j], 32, 64); ss[j] += __shfl_down(ss[j], 16, 64);
      if (quad == 0) {
        int o = o0 + wn + j * 16 + lr;
        atomicAdd(&stat[o * 2], s[j]);
        atomicAdd(&stat[o * 2 + 1], ss[j]);
      }
    }
  } else {
    const int cv0 = (t - 4) * 128;
    gemm_core_async<128, 128, 64>(wvb + (size_t)cv0 * 512, 512,
                                  xt + ((size_t)b * 4096 + n0) * 512, 512, 512,
                                  As, Bs, acc);
#pragma unroll
    for (int i = 0; i < 4; ++i)
#pragma unroll
      for (int j = 0; j < 4; ++j)
#pragma unroll
        for (int r = 0; r < 4; ++r) {
          int row = wm + i * 16 + quad * 4 + r, col = wn + j * 16 + lr;
          v[((size_t)b * 256 + cv0 + row) * 4096 + n0 + col] =
              f2s(acc[i * 4 + j][r] + bv[cv0 + row]);
        }
  }
}

// ---------------------------------------------------------------------------
// BN+ReLU: q_t[n][c] / k_t[n][c] bf16 from z_t columns.
// ---------------------------------------------------------------------------
__global__ __launch_bounds__(256) void k_bnrelu(
    const unsigned short* __restrict__ zt, const float* __restrict__ stats_raw,
    const float* __restrict__ gq, const float* __restrict__ betaq,
    const float* __restrict__ gk, const float* __restrict__ betak,
    unsigned short* __restrict__ qt, unsigned short* __restrict__ kt)
{
  const int t = threadIdx.x;
  const float mA = stats_raw[t * 2] * (1.f / 16384.f);
  const float vA = stats_raw[t * 2 + 1] * (1.f / 16384.f) - mA * mA;
  const float scA = rsqrtf(vA + 1e-5f) * gq[t], beA = betaq[t];
  const float mB = stats_raw[(t + 256) * 2] * (1.f / 16384.f);
  const float vB = stats_raw[(t + 256) * 2 + 1] * (1.f / 16384.f) - mB * mB;
  const float scB = rsqrtf(vB + 1e-5f) * gk[t], beB = betak[t];
  const int r0 = blockIdx.x * 16;
  for (int r = r0; r < r0 + 16; ++r) {
    float a = s2f(zt[(size_t)r * 512 + t]);
    qt[(size_t)r * 256 + t] = f2s(fmaxf((a - mA) * scA + beA, 0.f));
    float c = s2f(zt[(size_t)r * 512 + t + 256]);
    kt[(size_t)r * 256 + t] = f2s(fmaxf((c - mB) * scB + beB, 0.f));
  }
}

// ---------------------------------------------------------------------------
// k_att: fused flash-style attention core (P stays in LDS; fixed-shift
// softmax exp(s/16-20), exact since q,k>=0).
// R5: LDS-BW reduction (R4 post-mortem: 800KB/step LDS traffic was ~80% of
// runtime at ~85-128 B/cyc/CU).
//   (a) K h=0 half held in registers (kfrag[16], 64 VGPR, loaded once in
//       prologue) -> S-h0 phase has ZERO LDS A-reads.      -128 KB/step
//   (b) V read DIRECT global->register B-frags (no stageV, no V LDS reads;
//       both rn-waves load identical frags -> L1 hit).     -192 KB/step
//   (c) XCD swizzle: grid (g=ms+2b, n) so lin%8==g clusters the 32 blocks
//       sharing a (b,ms) Q/V stream on one XCD (2MB hot set < 4MB L2).
// 480 KB/step (0.60x), 3 barriers/step (was 4).
// LDS 160 KiB: Ks 64K + BufA/BufB 32K (Q staging dbuf) + Ps 32K.
// 512 thr (8 waves 2(n) x 4(m|c)), grid (8 groups, 32 n-tiles).
// ---------------------------------------------------------------------------
__global__ __launch_bounds__(512, 2) void k_att(
    const unsigned short* __restrict__ qt, const unsigned short* __restrict__ kt,
    const unsigned short* __restrict__ v, float* __restrict__ opart,
    float* __restrict__ lsum)
{
  __shared__ __align__(16) unsigned short Ks[4 * 8192];
  __shared__ __align__(16) unsigned short BufA[2 * 8192];
  __shared__ __align__(16) unsigned short BufB[2 * 8192];
  __shared__ __align__(16) unsigned short Ps[2 * 8192];

  const int tid = threadIdx.x;
  const int lane = tid & 63, wave = tid >> 6;
  const int lr = lane & 15, quad = lane >> 4;
  const int sw = lr & 7;
  const int rl = lane >> 3;                  // row within 8-row segment
  const int vg = (lane & 7) ^ rl;            // swizzled global vec index
  const int rn = wave >> 2, cw = wave & 3;   // wave grid 2(n) x 4(m or c)

  const int ms = blockIdx.x & 1, b = blockIdx.x >> 1;   // g = ms + 2b = XCD
  const int n0 = blockIdx.y * 128;

  const unsigned short* Qg = qt + (size_t)(b * 4096 + ms * 2048) * 256;
  const unsigned short* Vg = v + (size_t)(b * 256) * 4096 + ms * 2048;

  // stage Q panel [128m][128c] (t-row, c-half h) -> dst (32 segs of 1024B)
  auto stageQ = [&](unsigned short* dst, int trow, int h) {
#pragma unroll
    for (int s = wave; s < 32; s += 8) {
      const unsigned short* g = Qg
          + (size_t)(trow * 128 + (s & 15) * 8 + rl) * 256
          + h * 128 + (s >> 4) * 64 + vg * 8;
      __builtin_amdgcn_global_load_lds(
          (__attribute__((address_space(1))) void*)g,
          (__attribute__((address_space(3))) void*)(dst + s * 512), 16, 0, 0);
    }
  };
  // direct global->reg V B-frags for chunk ch: vf[kk][j] = V[c][m] 16B/lane
  auto loadV = [&](bfx8 (&vf)[2][4], int trow, int ch) {
#pragma unroll
    for (int kk = 0; kk < 2; ++kk)
#pragma unroll
      for (int j = 0; j < 4; ++j)
        vf[kk][j] = *(const bfx8*)(Vg
            + (size_t)(cw * 64 + j * 16 + lr) * 4096
            + trow * 128 + ch * 64 + kk * 32 + quad * 8);
  };

  f32x4 oacc[16] = {};
  float rsum[16] = {};
  const float C1 = 0.0625f * 1.44269504f;    // log2(e)/16
  const float C0 = -20.0f * 1.44269504f;     // -20*log2(e)

  // ---- prologue: K tile [128n][256c] (4 panels) + Q(0,h0) -> A ----
  {
    const unsigned short* Kg = kt + (size_t)(b * 4096 + n0) * 256;
#pragma unroll
    for (int s = wave; s < 64; s += 8) {
      const unsigned short* g = Kg + (size_t)((s & 15) * 8 + rl) * 256
                                + (s >> 4) * 64 + vg * 8;
      __builtin_amdgcn_global_load_lds(
          (__attribute__((address_space(1))) void*)g,
          (__attribute__((address_space(3))) void*)(Ks + s * 512), 16, 0, 0);
    }
  }
  stageQ(BufA, 0, 0);
  __syncthreads();

  // K h=0 fragments -> registers (read once; panels 0,1 dead afterwards)
  bfx8 kfrag[16];                            // [i][p2][kk] -> (i*2+p2)*2+kk
#pragma unroll
  for (int i = 0; i < 4; ++i)
#pragma unroll
    for (int p2 = 0; p2 < 2; ++p2)
#pragma unroll
      for (int kk = 0; kk < 2; ++kk)
        kfrag[(i * 2 + p2) * 2 + kk] = *(const bfx8*)(Ks + p2 * 8192
            + (rn * 64 + i * 16 + lr) * 64 + (((quad + kk * 4) ^ sw) << 3));

#pragma unroll 1
  for (int t = 0; t < 16; ++t) {
    f32x4 sacc[8] = {};
    bfx8 vf0[2][4], vf1[2][4];

    // compute O chunk ch from reg V-frags (P from Ps panel ch)
    auto computeO = [&](const bfx8 (&vf)[2][4], int ch) {
#pragma unroll
      for (int kk = 0; kk < 2; ++kk) {
        const int kv = kk * 4;
        bfx8 ap[4];
#pragma unroll
        for (int i = 0; i < 4; ++i)
          ap[i] = *(const bfx8*)(Ps + ch * 8192
                   + (rn * 64 + i * 16 + lr) * 64 + (((quad + kv) ^ sw) << 3));
#pragma unroll
        for (int i = 0; i < 4; ++i)
#pragma unroll
          for (int j = 0; j < 4; ++j)
            oacc[i * 4 + j] = __builtin_amdgcn_mfma_f32_16x16x32_bf16(
                ap[i], vf[kk][j], oacc[i * 4 + j], 0, 0, 0);
      }
    };

    // ---- p0: issue V(t,0)->reg; prefetch Q(t,h1)->B; S-h0 (K from regs) --
    loadV(vf0, t, 0);
    stageQ(BufB, t, 1);
#pragma unroll
    for (int p2 = 0; p2 < 2; ++p2)
#pragma unroll
      for (int kk = 0; kk < 2; ++kk) {
        const int kv = kk * 4;
        bfx8 bq[2];
#pragma unroll
        for (int j = 0; j < 2; ++j)
          bq[j] = *(const bfx8*)(BufA + p2 * 8192
                   + (cw * 32 + j * 16 + lr) * 64 + (((quad + kv) ^ sw) << 3));
#pragma unroll
        for (int i = 0; i < 4; ++i)
#pragma unroll
          for (int j = 0; j < 2; ++j)
            sacc[i * 2 + j] = __builtin_amdgcn_mfma_f32_16x16x32_bf16(
                kfrag[(i * 2 + p2) * 2 + kk], bq[j], sacc[i * 2 + j], 0, 0, 0);
      }
    __syncthreads();

    // ---- p1: prefetch Q(t+1,h0)->A; S-h1 (K from LDS panels 2,3); exp ----
    if (t < 15) stageQ(BufA, t + 1, 0);
#pragma unroll
    for (int p2 = 0; p2 < 2; ++p2)
#pragma unroll
      for (int kk = 0; kk < 2; ++kk) {
        const int kv = kk * 4;
        bfx8 af[4], bq[2];
#pragma unroll
        for (int i = 0; i < 4; ++i)
          af[i] = *(const bfx8*)(Ks + (2 + p2) * 8192
                   + (rn * 64 + i * 16 + lr) * 64 + (((quad + kv) ^ sw) << 3));
#pragma unroll
        for (int j = 0; j < 2; ++j)
          bq[j] = *(const bfx8*)(BufB + p2 * 8192
                   + (cw * 32 + j * 16 + lr) * 64 + (((quad + kv) ^ sw) << 3));
#pragma unroll
        for (int i = 0; i < 4; ++i)
#pragma unroll
          for (int j = 0; j < 2; ++j)
            sacc[i * 2 + j] = __builtin_amdgcn_mfma_f32_16x16x32_bf16(
                af[i], bq[j], sacc[i * 2 + j], 0, 0, 0);
      }
    // exp + P write to LDS (both panels), swizzled like gemm_core
#pragma unroll
    for (int i = 0; i < 4; ++i)
#pragma unroll
      for (int j = 0; j < 2; ++j)
#pragma unroll
        for (int r = 0; r < 4; ++r) {
          float p = __builtin_amdgcn_exp2f(fmaf(sacc[i * 2 + j][r], C1, C0));
          rsum[i * 4 + r] += p;
          const int row = rn * 64 + i * 16 + quad * 4 + r;
          const int cvec = cw * 4 + j * 2 + (lr >> 3);   // m_col>>3
          Ps[(cvec >> 3) * 8192 + row * 64
             + (((cvec & 7) ^ (row & 7)) << 3) + (lr & 7)] = f2s(p);
        }
    __syncthreads();

    // ---- p2: issue V(t,1)->reg; O-ch0 from vf0 ----
    loadV(vf1, t, 1);
    computeO(vf0, 0);

    // ---- p3: O-ch1 from vf1 ----
    computeO(vf1, 1);
    __syncthreads();
  }

  // ---- epilogue: fp32 partials + lsum atomics ----
  float* op = opart + ((size_t)(ms * 4 + b) * 4096 + n0) * 256;
#pragma unroll
  for (int i = 0; i < 4; ++i)
#pragma unroll
    for (int j = 0; j < 4; ++j)
#pragma unroll
      for (int r = 0; r < 4; ++r) {
        const int row = rn * 64 + i * 16 + quad * 4 + r;
        const int col = cw * 64 + j * 16 + lr;
        op[(size_t)row * 256 + col] = oacc[i * 4 + j][r];
      }
  float* l = lsum + b * 4096 + n0;
#pragma unroll
  for (int i = 0; i < 4; ++i)
#pragma unroll
    for (int r = 0; r < 4; ++r) {
      float rs = rsum[i * 4 + r];
      rs += __shfl_down(rs, 8, 16);
      rs += __shfl_down(rs, 4, 16);
      rs += __shfl_down(rs, 2, 16);
      rs += __shfl_down(rs, 1, 16);
      if (lr == 0) atomicAdd(&l[rn * 64 + i * 16 + quad * 4 + r], rs);
    }
}

// ---------------------------------------------------------------------------
// k_red: ctx[b,n][c] = (opart[0][b,n][c] + opart[1][b,n][c]) / lsum[b][n]
// grid 16384 (b*4096+n) x 256 (c). Coalesced.
// ---------------------------------------------------------------------------
__global__ __launch_bounds__(256) void k_red(
    const float* __restrict__ opart, const float* __restrict__ lsum,
    unsigned short* __restrict__ ctx)
{
  const int g = blockIdx.x, c = threadIdx.x;     // g = b*4096 + n
  const float s = opart[(size_t)g * 256 + c]
                + opart[((size_t)g + 16384) * 256 + c];
  ctx[(size_t)g * 256 + c] = f2s(s / lsum[g]);
}

// ---------------------------------------------------------------------------
// Out: out[b][o][n] = sum_cv wW[o][cv] ctx[b,n][cv] + bW[o] + x[b][o][n]
// ---------------------------------------------------------------------------
__global__ __launch_bounds__(256) void k_out(
    const unsigned short* __restrict__ wWb, const float* __restrict__ bW,
    const unsigned short* __restrict__ ctx, const float* __restrict__ x,
    float* __restrict__ out)
{
  __shared__ __align__(16) unsigned short As[128 * 64], Bs[128 * 64];
  f32x4 acc[16] = {};
  const int b = blockIdx.z, n0 = blockIdx.x * 128, o0 = blockIdx.y * 128;
  gemm_core_async<128, 128, 64>(wWb + (size_t)o0 * 256, 256,
                                ctx + ((size_t)b * 4096 + n0) * 256, 256, 256,
                                As, Bs, acc);
  const int lane = threadIdx.x & 63, wave = threadIdx.x >> 6;
  const int lr = lane & 15, quad = lane >> 4;
  const int wm = (wave >> 1) * 64, wn = (wave & 1) * 64;
#pragma unroll
  for (int i = 0; i < 4; ++i)
#pragma unroll
    for (int j = 0; j < 4; ++j)
#pragma unroll
      for (int r = 0; r < 4; ++r) {
        int row = wm + i * 16 + quad * 4 + r, col = wn + j * 16 + lr;
        size_t idx = ((size_t)b * 512 + o0 + row) * 4096 + n0 + col;
        out[idx] = acc[i * 4 + j][r] + bW[o0 + row] + x[idx];
      }
}

// ---------------------------------------------------------------------------
extern "C" void kernel_launch(void* const* d_in, const int* in_sizes, int n_in,
                              void* d_out, int out_size, void* d_ws, size_t ws_size,
                              hipStream_t stream)
{
  const float* x     = (const float*)d_in[0];
  const float* wq    = (const float*)d_in[1];
  // d_in[2] = bq: cancelled exactly by BN mean-subtraction
  const float* gq    = (const float*)d_in[3];
  const float* betaq = (const float*)d_in[4];
  const float* wk    = (const float*)d_in[5];
  // d_in[6] = bk: cancelled
  const float* gk    = (const float*)d_in[7];
  const float* betak = (const float*)d_in[8];
  const float* wv    = (const float*)d_in[9];
  const float* bv    = (const float*)d_in[10];
  const float* wW    = (const float*)d_in[11];
  const float* bW    = (const float*)d_in[12];
  float* out = (float*)d_out;

  // workspace layout (ws_size = 256 MiB)
  char* ws = (char*)d_ws;
  unsigned short* qt   = (unsigned short*)(ws);              //  8 MiB [4*4096,256]
  unsigned short* kt   = (unsigned short*)(ws + 8388608);    //  8 MiB
  unsigned short* v    = (unsigned short*)(ws + 16777216);   //  8 MiB [4,256,4096]
  unsigned short* ctx  = (unsigned short*)(ws + 25165824);   //  8 MiB [4*4096,256]
  unsigned short* wqk  = (unsigned short*)(ws + 33554432);   // 512 KiB [512,512]
  unsigned short* wvb  = (unsigned short*)(ws + 34078720);   // 256 KiB [256,512]
  unsigned short* wWb  = (unsigned short*)(ws + 34340864);   // 256 KiB [512,256]
  float*          stat = (float*)         (ws + 34603008);   //   4 KiB
  float*          lsum = (float*)         (ws + 34607104);   //  64 KiB [4][4096]
  float*          opart= (float*)         (ws + 35651584);   // 32 MiB [2,4,4096,256] fp32
  unsigned short* xt   = (unsigned short*)(ws + 35651584);   // 16 MiB, aliases opart
  unsigned short* zt   = (unsigned short*)(ws + 52428800);   // 16 MiB, aliases opart
                                                             // (xt dead after k_qkv,
                                                             //  zt dead after k_bnrelu,
                                                             //  both before k_att)

  (void)hipMemsetAsync(stat, 0, 69632, stream);  // stat (4K) + lsum (64K)
  k_pre   <<<3072, 256, 0, stream>>>(x, xt, wq, wk, wv, wW, wqk, wvb, wWb);
  k_qkv   <<<dim3(32, 6, 4), 256, 0, stream>>>(xt, wqk, wvb, bv, zt, v, stat);
  k_bnrelu<<<1024, 256, 0, stream>>>(zt, stat, gq, betaq, gk, betak, qt, kt);
  // grid.x = ms + 2*b (8 groups): lin%8 == group -> same-(b,ms) blocks
  // cluster on one XCD (L2 locality for the shared Q/V stream).
  k_att   <<<dim3(8, 32), 512, 0, stream>>>(qt, kt, v, opart, lsum);
  k_red   <<<16384, 256, 0, stream>>>(opart, lsum, ctx);
  k_out   <<<dim3(32, 4, 4), 256, 0, stream>>>(wWb, bW, ctx, x, out);
}

// Round 6
// 390.173 us; speedup vs baseline: 1.0336x; 1.0336x over previous
//
#include <hip/hip_runtime.h>

typedef __attribute__((ext_vector_type(8))) __bf16 bfx8;
typedef __attribute__((ext_vector_type(4))) float f32x4;

__device__ __forceinline__ float s2f(unsigned short s) {
  return __uint_as_float((unsigned int)s << 16);
}
// round-half-up bf16 convert (2 VALU ops; tie-only difference vs RNE)
__device__ __forceinline__ unsigned short f2s(float f) {
  return (unsigned short)((__float_as_uint(f) + 0x8000u) >> 16);
}

// ---------------------------------------------------------------------------
// Async MFMA GEMM core (global_load_lds staging, XOR-swizzled; R5-verified:
// SQ_LDS_BANK_CONFLICT == 0). Both operands [row][k] k-contiguous.
// D[m][n] = sum_k Ag[m][k]*Bg[n][k]. 256 thr = 4 waves 2x2.
// ---------------------------------------------------------------------------
template<int BM, int BN, int BK>
__device__ __forceinline__ void gemm_core_async(
    const unsigned short* __restrict__ Ag, int lda,
    const unsigned short* __restrict__ Bg, int ldb, int K,
    unsigned short* As, unsigned short* Bs, f32x4* acc)
{
  static_assert(BK == 64, "BK must be 64 (128B rows)");
  constexpr int WM = BM / 2, WN = BN / 2;
  constexpr int MT = WM / 16, NT = WN / 16;
  constexpr int SA = BM / 8, SB = BN / 8;   // 1024B segments per tile
  const int tid = threadIdx.x;
  const int lane = tid & 63, wave = tid >> 6;
  const int lr = lane & 15, quad = lane >> 4;
  const int sw = lr & 7;
  const int rl = lane >> 3;                  // row within segment (0..7)
  const int vg = (lane & 7) ^ rl;            // swizzled global vec index
  const int wm = (wave >> 1) * WM, wn = (wave & 1) * WN;

  for (int k0 = 0; k0 < K; k0 += BK) {
#pragma unroll
    for (int s = wave; s < SA; s += 4) {
      const unsigned short* g = Ag + (size_t)(s * 8 + rl) * lda + k0 + vg * 8;
      __builtin_amdgcn_global_load_lds(
          (__attribute__((address_space(1))) void*)g,
          (__attribute__((address_space(3))) void*)(As + s * 512), 16, 0, 0);
    }
#pragma unroll
    for (int s = wave; s < SB; s += 4) {
      const unsigned short* g = Bg + (size_t)(s * 8 + rl) * ldb + k0 + vg * 8;
      __builtin_amdgcn_global_load_lds(
          (__attribute__((address_space(1))) void*)g,
          (__attribute__((address_space(3))) void*)(Bs + s * 512), 16, 0, 0);
    }
    __syncthreads();
#pragma unroll
    for (int kk = 0; kk < BK; kk += 32) {
      const int kv = kk >> 3;                // 0 or 4
      bfx8 af[MT], bfr[NT];
#pragma unroll
      for (int i = 0; i < MT; ++i)
        af[i] = *(const bfx8*)(As + (wm + i * 16 + lr) * BK
                               + (((quad + kv) ^ sw) << 3));
#pragma unroll
      for (int j = 0; j < NT; ++j)
        bfr[j] = *(const bfx8*)(Bs + (wn + j * 16 + lr) * BK
                                + (((quad + kv) ^ sw) << 3));
#pragma unroll
      for (int i = 0; i < MT; ++i)
#pragma unroll
        for (int j = 0; j < NT; ++j)
          acc[i * NT + j] = __builtin_amdgcn_mfma_f32_16x16x32_bf16(
              af[i], bfr[j], acc[i * NT + j], 0, 0, 0);
    }
    __syncthreads();
  }
}

// ---------------------------------------------------------------------------
// k_pre: fused x transpose (fp32 [4][512][4096] -> bf16 x_t [4][4096][512],
// blocks 0..2047) and weight converts (blocks 2048..3071).
// ---------------------------------------------------------------------------
__global__ __launch_bounds__(256) void k_pre(
    const float* __restrict__ x, unsigned short* __restrict__ xt,
    const float* __restrict__ wq, const float* __restrict__ wk,
    const float* __restrict__ wv, const float* __restrict__ wW,
    unsigned short* __restrict__ wqk, unsigned short* __restrict__ wvb,
    unsigned short* __restrict__ wWb)
{
  const int bid = blockIdx.x, tid = threadIdx.x;
  if (bid < 2048) {
    __shared__ float t[64][65];
    const int b = bid >> 9, c0 = ((bid >> 6) & 7) * 64, n0 = (bid & 63) * 64;
    const float* xb = x + ((size_t)b << 21);
    const int hi = tid >> 6, lo = tid & 63;
#pragma unroll
    for (int p = 0; p < 16; ++p)
      t[hi + p * 4][lo] = xb[(size_t)(c0 + hi + p * 4) * 4096 + n0 + lo];
    __syncthreads();
    unsigned short* xtb = xt + ((size_t)b << 21);
#pragma unroll
    for (int p = 0; p < 16; ++p)
      xtb[(size_t)(n0 + hi + p * 4) * 512 + c0 + lo] = f2s(t[lo][hi + p * 4]);
  } else {
    int i = (bid - 2048) * 256 + tid;              // i < 262144
    wqk[i] = f2s(i < 131072 ? wq[i] : wk[i - 131072]);
    if (i < 131072) { wvb[i] = f2s(wv[i]); wWb[i] = f2s(wW[i]); }
  }
}

// ---------------------------------------------------------------------------
// k_qkv: fused QK GEMM (+fp32 BN stats partials in epilogue) and V GEMM.
// ---------------------------------------------------------------------------
__global__ __launch_bounds__(256) void k_qkv(
    const unsigned short* __restrict__ xt, const unsigned short* __restrict__ wqk,
    const unsigned short* __restrict__ wvb, const float* __restrict__ bv,
    unsigned short* __restrict__ zt, unsigned short* __restrict__ v,
    float* __restrict__ stat)
{
  __shared__ __align__(16) unsigned short As[128 * 64], Bs[128 * 64];
  f32x4 acc[16] = {};
  const int b = blockIdx.z, n0 = blockIdx.x * 128, t = blockIdx.y;
  const int lane = threadIdx.x & 63, wave = threadIdx.x >> 6;
  const int lr = lane & 15, quad = lane >> 4;
  const int wm = (wave >> 1) * 64, wn = (wave & 1) * 64;

  if (t < 4) {
    const int o0 = t * 128;
    gemm_core_async<128, 128, 64>(xt + ((size_t)b * 4096 + n0) * 512, 512,
                                  wqk + (size_t)o0 * 512, 512, 512, As, Bs, acc);
    float s[4] = {}, ss[4] = {};
#pragma unroll
    for (int i = 0; i < 4; ++i)
#pragma unroll
      for (int j = 0; j < 4; ++j)
#pragma unroll
        for (int r = 0; r < 4; ++r) {
          float a = acc[i * 4 + j][r];
          int row = wm + i * 16 + quad * 4 + r, col = wn + j * 16 + lr;
          zt[((size_t)b * 4096 + n0 + row) * 512 + o0 + col] = f2s(a);
          s[j] += a; ss[j] += a * a;
        }
#pragma unroll
    for (int j = 0; j < 4; ++j) {
      s[j]  += __shfl_down(s[j], 32, 64);  s[j]  += __shfl_down(s[j], 16, 64);
      ss[j] += __shfl_down(ss[j], 32, 64); ss[j] += __shfl_down(ss[j], 16, 64);
      if (quad == 0) {
        int o = o0 + wn + j * 16 + lr;
        atomicAdd(&stat[o * 2], s[j]);
        atomicAdd(&stat[o * 2 + 1], ss[j]);
      }
    }
  } else {
    const int cv0 = (t - 4) * 128;
    gemm_core_async<128, 128, 64>(wvb + (size_t)cv0 * 512, 512,
                                  xt + ((size_t)b * 4096 + n0) * 512, 512, 512,
                                  As, Bs, acc);
#pragma unroll
    for (int i = 0; i < 4; ++i)
#pragma unroll
      for (int j = 0; j < 4; ++j)
#pragma unroll
        for (int r = 0; r < 4; ++r) {
          int row = wm + i * 16 + quad * 4 + r, col = wn + j * 16 + lr;
          v[((size_t)b * 256 + cv0 + row) * 4096 + n0 + col] =
              f2s(acc[i * 4 + j][r] + bv[cv0 + row]);
        }
  }
}

// ---------------------------------------------------------------------------
// BN+ReLU: q_t[n][c] / k_t[n][c] bf16 from z_t columns.
// ---------------------------------------------------------------------------
__global__ __launch_bounds__(256) void k_bnrelu(
    const unsigned short* __restrict__ zt, const float* __restrict__ stats_raw,
    const float* __restrict__ gq, const float* __restrict__ betaq,
    const float* __restrict__ gk, const float* __restrict__ betak,
    unsigned short* __restrict__ qt, unsigned short* __restrict__ kt)
{
  const int t = threadIdx.x;
  const float mA = stats_raw[t * 2] * (1.f / 16384.f);
  const float vA = stats_raw[t * 2 + 1] * (1.f / 16384.f) - mA * mA;
  const float scA = rsqrtf(vA + 1e-5f) * gq[t], beA = betaq[t];
  const float mB = stats_raw[(t + 256) * 2] * (1.f / 16384.f);
  const float vB = stats_raw[(t + 256) * 2 + 1] * (1.f / 16384.f) - mB * mB;
  const float scB = rsqrtf(vB + 1e-5f) * gk[t], beB = betak[t];
  const int r0 = blockIdx.x * 16;
  for (int r = r0; r < r0 + 16; ++r) {
    float a = s2f(zt[(size_t)r * 512 + t]);
    qt[(size_t)r * 256 + t] = f2s(fmaxf((a - mA) * scA + beA, 0.f));
    float c = s2f(zt[(size_t)r * 512 + t + 256]);
    kt[(size_t)r * 256 + t] = f2s(fmaxf((c - mB) * scB + beB, 0.f));
  }
}

// ---------------------------------------------------------------------------
// k_att: fused flash-style attention core (P stays in LDS; fixed-shift
// softmax exp(s/16-20), exact since q,k>=0). R6 = R4 structure (88.9 us,
// verified; R5's global->reg V gather regressed 2.8x — 8KB-stride 16B/lane
// loads are 64 cache lines/wave, transaction-bound) plus:
//   (a) kfrag: K h=0 half in registers (64 VGPR, read from LDS ONCE in the
//       prologue). S-h0 phase has zero LDS A-reads: LDS read volume
//       640->512 KB/step and S-h0 MFMAs wait only on Q's lgkm.
//   (b) T5 s_setprio(1) around each MFMA cluster.
// Phases per m-step (4 barriers):
//   p0: stage Q(t,h1)->B  | S-h0 (K from kfrag, Q from A) | sync
//   p1: stage V(t,0) ->A  | S-h1 (K LDS panels 2,3; Q from B); exp+P->Ps | sync
//   p2: stage V(t,1) ->B  | O-ch0 from A | sync
//   p3: stage Q(t+1,0)->A | O-ch1 from B | sync
// LDS 160 KiB: Ks 64K + BufA/BufB 32K + Ps 32K. 512 thr (8 waves 2n x 4m|c),
// grid (2 ms, 32 n, 4 b).
// ---------------------------------------------------------------------------
__global__ __launch_bounds__(512, 2) void k_att(
    const unsigned short* __restrict__ qt, const unsigned short* __restrict__ kt,
    const unsigned short* __restrict__ v, float* __restrict__ opart,
    float* __restrict__ lsum)
{
  __shared__ __align__(16) unsigned short Ks[4 * 8192];
  __shared__ __align__(16) unsigned short BufA[2 * 8192];
  __shared__ __align__(16) unsigned short BufB[2 * 8192];
  __shared__ __align__(16) unsigned short Ps[2 * 8192];

  const int tid = threadIdx.x;
  const int lane = tid & 63, wave = tid >> 6;
  const int lr = lane & 15, quad = lane >> 4;
  const int sw = lr & 7;
  const int rl = lane >> 3;                  // row within 8-row segment
  const int vg = (lane & 7) ^ rl;            // swizzled global vec index
  const int rn = wave >> 2, cw = wave & 3;   // wave grid 2(n) x 4(m or c)

  const int ms = blockIdx.x, n0 = blockIdx.y * 128, b = blockIdx.z;

  const unsigned short* Qg = qt + (size_t)(b * 4096 + ms * 2048) * 256;
  const unsigned short* Vg = v + (size_t)(b * 256) * 4096 + ms * 2048;

  // stage Q panel [128m][128c] (t-row, c-half h) -> dst (32 segs of 1024B)
  auto stageQ = [&](unsigned short* dst, int trow, int h) {
#pragma unroll
    for (int s = wave; s < 32; s += 8) {
      const unsigned short* g = Qg
          + (size_t)(trow * 128 + (s & 15) * 8 + rl) * 256
          + h * 128 + (s >> 4) * 64 + vg * 8;
      __builtin_amdgcn_global_load_lds(
          (__attribute__((address_space(1))) void*)g,
          (__attribute__((address_space(3))) void*)(dst + s * 512), 16, 0, 0);
    }
  };
  // stage V chunk [256c][64m] at m = trow*128 + ch*64 -> dst (coalesced)
  auto stageV = [&](unsigned short* dst, int trow, int ch) {
#pragma unroll
    for (int s = wave; s < 32; s += 8) {
      const unsigned short* g = Vg + (size_t)(s * 8 + rl) * 4096
                                + trow * 128 + ch * 64 + vg * 8;
      __builtin_amdgcn_global_load_lds(
          (__attribute__((address_space(1))) void*)g,
          (__attribute__((address_space(3))) void*)(dst + s * 512), 16, 0, 0);
    }
  };

  f32x4 oacc[16] = {};
  float rsum[16] = {};
  const float C1 = 0.0625f * 1.44269504f;    // log2(e)/16
  const float C0 = -20.0f * 1.44269504f;     // -20*log2(e)

  // ---- prologue: K tile [128n][256c] (4 panels) + Q(0,h0) -> A ----
  {
    const unsigned short* Kg = kt + (size_t)(b * 4096 + n0) * 256;
#pragma unroll
    for (int s = wave; s < 64; s += 8) {
      const unsigned short* g = Kg + (size_t)((s & 15) * 8 + rl) * 256
                                + (s >> 4) * 64 + vg * 8;
      __builtin_amdgcn_global_load_lds(
          (__attribute__((address_space(1))) void*)g,
          (__attribute__((address_space(3))) void*)(Ks + s * 512), 16, 0, 0);
    }
  }
  stageQ(BufA, 0, 0);
  __syncthreads();

  // K h=0 fragments -> registers (LDS read ONCE; panels 0,1 unused after)
  bfx8 kfrag[16];                            // [(i*2+p2)*2+kk]
#pragma unroll
  for (int i = 0; i < 4; ++i)
#pragma unroll
    for (int p2 = 0; p2 < 2; ++p2)
#pragma unroll
      for (int kk = 0; kk < 2; ++kk)
        kfrag[(i * 2 + p2) * 2 + kk] = *(const bfx8*)(Ks + p2 * 8192
            + (rn * 64 + i * 16 + lr) * 64 + (((quad + kk * 4) ^ sw) << 3));

#pragma unroll 1
  for (int t = 0; t < 16; ++t) {
    f32x4 sacc[8] = {};

    // compute O chunk ch from staged V buffer Vb (P from Ps panel ch)
    auto computeO = [&](const unsigned short* Vb, int ch) {
      __builtin_amdgcn_s_setprio(1);
#pragma unroll
      for (int kk = 0; kk < 2; ++kk) {
        const int kv = kk * 4;
        bfx8 ap[4], bvf[4];
#pragma unroll
        for (int i = 0; i < 4; ++i)
          ap[i] = *(const bfx8*)(Ps + ch * 8192
                   + (rn * 64 + i * 16 + lr) * 64 + (((quad + kv) ^ sw) << 3));
#pragma unroll
        for (int j = 0; j < 4; ++j)
          bvf[j] = *(const bfx8*)(Vb
                   + (cw * 64 + j * 16 + lr) * 64 + (((quad + kv) ^ sw) << 3));
#pragma unroll
        for (int i = 0; i < 4; ++i)
#pragma unroll
          for (int j = 0; j < 4; ++j)
            oacc[i * 4 + j] = __builtin_amdgcn_mfma_f32_16x16x32_bf16(
                ap[i], bvf[j], oacc[i * 4 + j], 0, 0, 0);
      }
      __builtin_amdgcn_s_setprio(0);
    };

    // ---- p0: prefetch Q(t,h1)->B; S-h0 (K from kfrag, Q from A) ----
    stageQ(BufB, t, 1);
    __builtin_amdgcn_s_setprio(1);
#pragma unroll
    for (int p2 = 0; p2 < 2; ++p2)
#pragma unroll
      for (int kk = 0; kk < 2; ++kk) {
        const int kv = kk * 4;
        bfx8 bq[2];
#pragma unroll
        for (int j = 0; j < 2; ++j)
          bq[j] = *(const bfx8*)(BufA + p2 * 8192
                   + (cw * 32 + j * 16 + lr) * 64 + (((quad + kv) ^ sw) << 3));
#pragma unroll
        for (int i = 0; i < 4; ++i)
#pragma unroll
          for (int j = 0; j < 2; ++j)
            sacc[i * 2 + j] = __builtin_amdgcn_mfma_f32_16x16x32_bf16(
                kfrag[(i * 2 + p2) * 2 + kk], bq[j], sacc[i * 2 + j], 0, 0, 0);
      }
    __builtin_amdgcn_s_setprio(0);
    __syncthreads();

    // ---- p1: prefetch V(t,0)->A; S-h1 (K LDS panels 2,3; Q from B); exp --
    stageV(BufA, t, 0);
    __builtin_amdgcn_s_setprio(1);
#pragma unroll
    for (int p2 = 0; p2 < 2; ++p2)
#pragma unroll
      for (int kk = 0; kk < 2; ++kk) {
        const int kv = kk * 4;
        bfx8 af[4], bq[2];
#pragma unroll
        for (int i = 0; i < 4; ++i)
          af[i] = *(const bfx8*)(Ks + (2 + p2) * 8192
                   + (rn * 64 + i * 16 + lr) * 64 + (((quad + kv) ^ sw) << 3));
#pragma unroll
        for (int j = 0; j < 2; ++j)
          bq[j] = *(const bfx8*)(BufB + p2 * 8192
                   + (cw * 32 + j * 16 + lr) * 64 + (((quad + kv) ^ sw) << 3));
#pragma unroll
        for (int i = 0; i < 4; ++i)
#pragma unroll
          for (int j = 0; j < 2; ++j)
            sacc[i * 2 + j] = __builtin_amdgcn_mfma_f32_16x16x32_bf16(
                af[i], bq[j], sacc[i * 2 + j], 0, 0, 0);
      }
    __builtin_amdgcn_s_setprio(0);
    // exp + P write to LDS (both panels), swizzled like gemm_core
#pragma unroll
    for (int i = 0; i < 4; ++i)
#pragma unroll
      for (int j = 0; j < 2; ++j)
#pragma unroll
        for (int r = 0; r < 4; ++r) {
          float p = __builtin_amdgcn_exp2f(fmaf(sacc[i * 2 + j][r], C1, C0));
          rsum[i * 4 + r] += p;
          const int row = rn * 64 + i * 16 + quad * 4 + r;
          const int cvec = cw * 4 + j * 2 + (lr >> 3);   // m_col>>3
          Ps[(cvec >> 3) * 8192 + row * 64
             + (((cvec & 7) ^ (row & 7)) << 3) + (lr & 7)] = f2s(p);
        }
    __syncthreads();

    // ---- p2: prefetch V(t,1)->B; O-ch0 from A (=V0) ----
    stageV(BufB, t, 1);
    computeO(BufA, 0);
    __syncthreads();

    // ---- p3: prefetch Q(t+1,0)->A; O-ch1 from B (=V1) ----
    if (t < 15) stageQ(BufA, t + 1, 0);
    computeO(BufB, 1);
    __syncthreads();
  }

  // ---- epilogue: fp32 partials + lsum atomics ----
  float* op = opart + ((size_t)(ms * 4 + b) * 4096 + n0) * 256;
#pragma unroll
  for (int i = 0; i < 4; ++i)
#pragma unroll
    for (int j = 0; j < 4; ++j)
#pragma unroll
      for (int r = 0; r < 4; ++r) {
        const int row = rn * 64 + i * 16 + quad * 4 + r;
        const int col = cw * 64 + j * 16 + lr;
        op[(size_t)row * 256 + col] = oacc[i * 4 + j][r];
      }
  float* l = lsum + b * 4096 + n0;
#pragma unroll
  for (int i = 0; i < 4; ++i)
#pragma unroll
    for (int r = 0; r < 4; ++r) {
      float rs = rsum[i * 4 + r];
      rs += __shfl_down(rs, 8, 16);
      rs += __shfl_down(rs, 4, 16);
      rs += __shfl_down(rs, 2, 16);
      rs += __shfl_down(rs, 1, 16);
      if (lr == 0) atomicAdd(&l[rn * 64 + i * 16 + quad * 4 + r], rs);
    }
}

// ---------------------------------------------------------------------------
// k_red: ctx[b,n][c] = (opart[0][b,n][c] + opart[1][b,n][c]) / lsum[b][n]
// grid 16384 (b*4096+n) x 256 (c). Coalesced.
// ---------------------------------------------------------------------------
__global__ __launch_bounds__(256) void k_red(
    const float* __restrict__ opart, const float* __restrict__ lsum,
    unsigned short* __restrict__ ctx)
{
  const int g = blockIdx.x, c = threadIdx.x;     // g = b*4096 + n
  const float s = opart[(size_t)g * 256 + c]
                + opart[((size_t)g + 16384) * 256 + c];
  ctx[(size_t)g * 256 + c] = f2s(s / lsum[g]);
}

// ---------------------------------------------------------------------------
// Out: out[b][o][n] = sum_cv wW[o][cv] ctx[b,n][cv] + bW[o] + x[b][o][n]
// ---------------------------------------------------------------------------
__global__ __launch_bounds__(256) void k_out(
    const unsigned short* __restrict__ wWb, const float* __restrict__ bW,
    const unsigned short* __restrict__ ctx, const float* __restrict__ x,
    float* __restrict__ out)
{
  __shared__ __align__(16) unsigned short As[128 * 64], Bs[128 * 64];
  f32x4 acc[16] = {};
  const int b = blockIdx.z, n0 = blockIdx.x * 128, o0 = blockIdx.y * 128;
  gemm_core_async<128, 128, 64>(wWb + (size_t)o0 * 256, 256,
                                ctx + ((size_t)b * 4096 + n0) * 256, 256, 256,
                                As, Bs, acc);
  const int lane = threadIdx.x & 63, wave = threadIdx.x >> 6;
  const int lr = lane & 15, quad = lane >> 4;
  const int wm = (wave >> 1) * 64, wn = (wave & 1) * 64;
#pragma unroll
  for (int i = 0; i < 4; ++i)
#pragma unroll
    for (int j = 0; j < 4; ++j)
#pragma unroll
      for (int r = 0; r < 4; ++r) {
        int row = wm + i * 16 + quad * 4 + r, col = wn + j * 16 + lr;
        size_t idx = ((size_t)b * 512 + o0 + row) * 4096 + n0 + col;
        out[idx] = acc[i * 4 + j][r] + bW[o0 + row] + x[idx];
      }
}

// ---------------------------------------------------------------------------
extern "C" void kernel_launch(void* const* d_in, const int* in_sizes, int n_in,
                              void* d_out, int out_size, void* d_ws, size_t ws_size,
                              hipStream_t stream)
{
  const float* x     = (const float*)d_in[0];
  const float* wq    = (const float*)d_in[1];
  // d_in[2] = bq: cancelled exactly by BN mean-subtraction
  const float* gq    = (const float*)d_in[3];
  const float* betaq = (const float*)d_in[4];
  const float* wk    = (const float*)d_in[5];
  // d_in[6] = bk: cancelled
  const float* gk    = (const float*)d_in[7];
  const float* betak = (const float*)d_in[8];
  const float* wv    = (const float*)d_in[9];
  const float* bv    = (const float*)d_in[10];
  const float* wW    = (const float*)d_in[11];
  const float* bW    = (const float*)d_in[12];
  float* out = (float*)d_out;

  // workspace layout (ws_size = 256 MiB)
  char* ws = (char*)d_ws;
  unsigned short* qt   = (unsigned short*)(ws);              //  8 MiB [4*4096,256]
  unsigned short* kt   = (unsigned short*)(ws + 8388608);    //  8 MiB
  unsigned short* v    = (unsigned short*)(ws + 16777216);   //  8 MiB [4,256,4096]
  unsigned short* ctx  = (unsigned short*)(ws + 25165824);   //  8 MiB [4*4096,256]
  unsigned short* wqk  = (unsigned short*)(ws + 33554432);   // 512 KiB [512,512]
  unsigned short* wvb  = (unsigned short*)(ws + 34078720);   // 256 KiB [256,512]
  unsigned short* wWb  = (unsigned short*)(ws + 34340864);   // 256 KiB [512,256]
  float*          stat = (float*)         (ws + 34603008);   //   4 KiB
  float*          lsum = (float*)         (ws + 34607104);   //  64 KiB [4][4096]
  float*          opart= (float*)         (ws + 35651584);   // 32 MiB [2,4,4096,256] fp32
  unsigned short* xt   = (unsigned short*)(ws + 35651584);   // 16 MiB, aliases opart
  unsigned short* zt   = (unsigned short*)(ws + 52428800);   // 16 MiB, aliases opart
                                                             // (xt dead after k_qkv,
                                                             //  zt dead after k_bnrelu,
                                                             //  both before k_att)

  (void)hipMemsetAsync(stat, 0, 69632, stream);  // stat (4K) + lsum (64K)
  k_pre   <<<3072, 256, 0, stream>>>(x, xt, wq, wk, wv, wW, wqk, wvb, wWb);
  k_qkv   <<<dim3(32, 6, 4), 256, 0, stream>>>(xt, wqk, wvb, bv, zt, v, stat);
  k_bnrelu<<<1024, 256, 0, stream>>>(zt, stat, gq, betaq, gk, betak, qt, kt);
  k_att   <<<dim3(2, 32, 4), 512, 0, stream>>>(qt, kt, v, opart, lsum);
  k_red   <<<16384, 256, 0, stream>>>(opart, lsum, ctx);
  k_out   <<<dim3(32, 4, 4), 256, 0, stream>>>(wWb, bW, ctx, x, out);
}

// Round 7
// 384.550 us; speedup vs baseline: 1.0487x; 1.0146x over previous
//
#include <hip/hip_runtime.h>

typedef __attribute__((ext_vector_type(8))) __bf16 bfx8;
typedef __attribute__((ext_vector_type(4))) float f32x4;

__device__ __forceinline__ float s2f(unsigned short s) {
  return __uint_as_float((unsigned int)s << 16);
}
// round-half-up bf16 convert (2 VALU ops; tie-only difference vs RNE)
__device__ __forceinline__ unsigned short f2s(float f) {
  return (unsigned short)((__float_as_uint(f) + 0x8000u) >> 16);
}

// ---------------------------------------------------------------------------
// Async MFMA GEMM core (global_load_lds staging, XOR-swizzled; R5-verified:
// SQ_LDS_BANK_CONFLICT == 0). Both operands [row][k] k-contiguous.
// D[m][n] = sum_k Ag[m][k]*Bg[n][k]. 256 thr = 4 waves 2x2.
// ---------------------------------------------------------------------------
template<int BM, int BN, int BK>
__device__ __forceinline__ void gemm_core_async(
    const unsigned short* __restrict__ Ag, int lda,
    const unsigned short* __restrict__ Bg, int ldb, int K,
    unsigned short* As, unsigned short* Bs, f32x4* acc)
{
  static_assert(BK == 64, "BK must be 64 (128B rows)");
  constexpr int WM = BM / 2, WN = BN / 2;
  constexpr int MT = WM / 16, NT = WN / 16;
  constexpr int SA = BM / 8, SB = BN / 8;   // 1024B segments per tile
  const int tid = threadIdx.x;
  const int lane = tid & 63, wave = tid >> 6;
  const int lr = lane & 15, quad = lane >> 4;
  const int sw = lr & 7;
  const int rl = lane >> 3;                  // row within segment (0..7)
  const int vg = (lane & 7) ^ rl;            // swizzled global vec index
  const int wm = (wave >> 1) * WM, wn = (wave & 1) * WN;

  for (int k0 = 0; k0 < K; k0 += BK) {
#pragma unroll
    for (int s = wave; s < SA; s += 4) {
      const unsigned short* g = Ag + (size_t)(s * 8 + rl) * lda + k0 + vg * 8;
      __builtin_amdgcn_global_load_lds(
          (__attribute__((address_space(1))) void*)g,
          (__attribute__((address_space(3))) void*)(As + s * 512), 16, 0, 0);
    }
#pragma unroll
    for (int s = wave; s < SB; s += 4) {
      const unsigned short* g = Bg + (size_t)(s * 8 + rl) * ldb + k0 + vg * 8;
      __builtin_amdgcn_global_load_lds(
          (__attribute__((address_space(1))) void*)g,
          (__attribute__((address_space(3))) void*)(Bs + s * 512), 16, 0, 0);
    }
    __syncthreads();
#pragma unroll
    for (int kk = 0; kk < BK; kk += 32) {
      const int kv = kk >> 3;                // 0 or 4
      bfx8 af[MT], bfr[NT];
#pragma unroll
      for (int i = 0; i < MT; ++i)
        af[i] = *(const bfx8*)(As + (wm + i * 16 + lr) * BK
                               + (((quad + kv) ^ sw) << 3));
#pragma unroll
      for (int j = 0; j < NT; ++j)
        bfr[j] = *(const bfx8*)(Bs + (wn + j * 16 + lr) * BK
                                + (((quad + kv) ^ sw) << 3));
#pragma unroll
      for (int i = 0; i < MT; ++i)
#pragma unroll
        for (int j = 0; j < NT; ++j)
          acc[i * NT + j] = __builtin_amdgcn_mfma_f32_16x16x32_bf16(
              af[i], bfr[j], acc[i * NT + j], 0, 0, 0);
    }
    __syncthreads();
  }
}

// ---------------------------------------------------------------------------
// k_pre: fused x transpose (fp32 [4][512][4096] -> bf16 x_t [4][4096][512],
// blocks 0..2047) and weight converts (blocks 2048..3071).
// ---------------------------------------------------------------------------
__global__ __launch_bounds__(256) void k_pre(
    const float* __restrict__ x, unsigned short* __restrict__ xt,
    const float* __restrict__ wq, const float* __restrict__ wk,
    const float* __restrict__ wv, const float* __restrict__ wW,
    unsigned short* __restrict__ wqk, unsigned short* __restrict__ wvb,
    unsigned short* __restrict__ wWb)
{
  const int bid = blockIdx.x, tid = threadIdx.x;
  if (bid < 2048) {
    __shared__ float t[64][65];
    const int b = bid >> 9, c0 = ((bid >> 6) & 7) * 64, n0 = (bid & 63) * 64;
    const float* xb = x + ((size_t)b << 21);
    const int hi = tid >> 6, lo = tid & 63;
#pragma unroll
    for (int p = 0; p < 16; ++p)
      t[hi + p * 4][lo] = xb[(size_t)(c0 + hi + p * 4) * 4096 + n0 + lo];
    __syncthreads();
    unsigned short* xtb = xt + ((size_t)b << 21);
#pragma unroll
    for (int p = 0; p < 16; ++p)
      xtb[(size_t)(n0 + hi + p * 4) * 512 + c0 + lo] = f2s(t[lo][hi + p * 4]);
  } else {
    int i = (bid - 2048) * 256 + tid;              // i < 262144
    wqk[i] = f2s(i < 131072 ? wq[i] : wk[i - 131072]);
    if (i < 131072) { wvb[i] = f2s(wv[i]); wWb[i] = f2s(wW[i]); }
  }
}

// ---------------------------------------------------------------------------
// k_qkv: fused QK GEMM (+fp32 BN stats partials in epilogue) and V GEMM.
// ---------------------------------------------------------------------------
__global__ __launch_bounds__(256) void k_qkv(
    const unsigned short* __restrict__ xt, const unsigned short* __restrict__ wqk,
    const unsigned short* __restrict__ wvb, const float* __restrict__ bv,
    unsigned short* __restrict__ zt, unsigned short* __restrict__ v,
    float* __restrict__ stat)
{
  __shared__ __align__(16) unsigned short As[128 * 64], Bs[128 * 64];
  f32x4 acc[16] = {};
  const int b = blockIdx.z, n0 = blockIdx.x * 128, t = blockIdx.y;
  const int lane = threadIdx.x & 63, wave = threadIdx.x >> 6;
  const int lr = lane & 15, quad = lane >> 4;
  const int wm = (wave >> 1) * 64, wn = (wave & 1) * 64;

  if (t < 4) {
    const int o0 = t * 128;
    gemm_core_async<128, 128, 64>(xt + ((size_t)b * 4096 + n0) * 512, 512,
                                  wqk + (size_t)o0 * 512, 512, 512, As, Bs, acc);
    float s[4] = {}, ss[4] = {};
#pragma unroll
    for (int i = 0; i < 4; ++i)
#pragma unroll
      for (int j = 0; j < 4; ++j)
#pragma unroll
        for (int r = 0; r < 4; ++r) {
          float a = acc[i * 4 + j][r];
          int row = wm + i * 16 + quad * 4 + r, col = wn + j * 16 + lr;
          zt[((size_t)b * 4096 + n0 + row) * 512 + o0 + col] = f2s(a);
          s[j] += a; ss[j] += a * a;
        }
#pragma unroll
    for (int j = 0; j < 4; ++j) {
      s[j]  += __shfl_down(s[j], 32, 64);  s[j]  += __shfl_down(s[j], 16, 64);
      ss[j] += __shfl_down(ss[j], 32, 64); ss[j] += __shfl_down(ss[j], 16, 64);
      if (quad == 0) {
        int o = o0 + wn + j * 16 + lr;
        atomicAdd(&stat[o * 2], s[j]);
        atomicAdd(&stat[o * 2 + 1], ss[j]);
      }
    }
  } else {
    const int cv0 = (t - 4) * 128;
    gemm_core_async<128, 128, 64>(wvb + (size_t)cv0 * 512, 512,
                                  xt + ((size_t)b * 4096 + n0) * 512, 512, 512,
                                  As, Bs, acc);
#pragma unroll
    for (int i = 0; i < 4; ++i)
#pragma unroll
      for (int j = 0; j < 4; ++j)
#pragma unroll
        for (int r = 0; r < 4; ++r) {
          int row = wm + i * 16 + quad * 4 + r, col = wn + j * 16 + lr;
          v[((size_t)b * 256 + cv0 + row) * 4096 + n0 + col] =
              f2s(acc[i * 4 + j][r] + bv[cv0 + row]);
        }
  }
}

// ---------------------------------------------------------------------------
// BN+ReLU: q_t[n][c] / k_t[n][c] bf16 from z_t columns.
// ---------------------------------------------------------------------------
__global__ __launch_bounds__(256) void k_bnrelu(
    const unsigned short* __restrict__ zt, const float* __restrict__ stats_raw,
    const float* __restrict__ gq, const float* __restrict__ betaq,
    const float* __restrict__ gk, const float* __restrict__ betak,
    unsigned short* __restrict__ qt, unsigned short* __restrict__ kt)
{
  const int t = threadIdx.x;
  const float mA = stats_raw[t * 2] * (1.f / 16384.f);
  const float vA = stats_raw[t * 2 + 1] * (1.f / 16384.f) - mA * mA;
  const float scA = rsqrtf(vA + 1e-5f) * gq[t], beA = betaq[t];
  const float mB = stats_raw[(t + 256) * 2] * (1.f / 16384.f);
  const float vB = stats_raw[(t + 256) * 2 + 1] * (1.f / 16384.f) - mB * mB;
  const float scB = rsqrtf(vB + 1e-5f) * gk[t], beB = betak[t];
  const int r0 = blockIdx.x * 16;
  for (int r = r0; r < r0 + 16; ++r) {
    float a = s2f(zt[(size_t)r * 512 + t]);
    qt[(size_t)r * 256 + t] = f2s(fmaxf((a - mA) * scA + beA, 0.f));
    float c = s2f(zt[(size_t)r * 512 + t + 256]);
    kt[(size_t)r * 256 + t] = f2s(fmaxf((c - mB) * scB + beB, 0.f));
  }
}

// ---------------------------------------------------------------------------
// k_att: fused flash-style attention core (P stays in LDS; fixed-shift
// softmax exp(s/16-20), exact since q,k>=0). R7 = R6 + amdgpu_waves_per_eu(2,2).
// R6 post-mortem: VGPR_Count stayed 128 (allocator targeted 4 waves/EU,
// unreachable: 160KB LDS caps at 1 block/CU = 2 waves/SIMD) -> kfrag spilled
// to scratch (WRITE +30MB = 256 blk x 128KB spill; FETCH 41->156MB spill
// re-reads). waves_per_eu(2,2) raises the budget to 256 VGPR so kfrag
// actually lives in registers.
// Phases per m-step (4 barriers):
//   p0: stage Q(t,h1)->B  | S-h0 (K from kfrag, Q from A) | sync
//   p1: stage V(t,0) ->A  | S-h1 (K LDS panels 2,3; Q from B); exp+P->Ps | sync
//   p2: stage V(t,1) ->B  | O-ch0 from A | sync
//   p3: stage Q(t+1,0)->A | O-ch1 from B | sync
// LDS 160 KiB: Ks 64K + BufA/BufB 32K + Ps 32K. 512 thr (8 waves 2n x 4m|c),
// grid (2 ms, 32 n, 4 b).
// ---------------------------------------------------------------------------
__global__ __launch_bounds__(512)
__attribute__((amdgpu_waves_per_eu(2, 2)))
void k_att(
    const unsigned short* __restrict__ qt, const unsigned short* __restrict__ kt,
    const unsigned short* __restrict__ v, float* __restrict__ opart,
    float* __restrict__ lsum)
{
  __shared__ __align__(16) unsigned short Ks[4 * 8192];
  __shared__ __align__(16) unsigned short BufA[2 * 8192];
  __shared__ __align__(16) unsigned short BufB[2 * 8192];
  __shared__ __align__(16) unsigned short Ps[2 * 8192];

  const int tid = threadIdx.x;
  const int lane = tid & 63, wave = tid >> 6;
  const int lr = lane & 15, quad = lane >> 4;
  const int sw = lr & 7;
  const int rl = lane >> 3;                  // row within 8-row segment
  const int vg = (lane & 7) ^ rl;            // swizzled global vec index
  const int rn = wave >> 2, cw = wave & 3;   // wave grid 2(n) x 4(m or c)

  const int ms = blockIdx.x, n0 = blockIdx.y * 128, b = blockIdx.z;

  const unsigned short* Qg = qt + (size_t)(b * 4096 + ms * 2048) * 256;
  const unsigned short* Vg = v + (size_t)(b * 256) * 4096 + ms * 2048;

  // stage Q panel [128m][128c] (t-row, c-half h) -> dst (32 segs of 1024B)
  auto stageQ = [&](unsigned short* dst, int trow, int h) {
#pragma unroll
    for (int s = wave; s < 32; s += 8) {
      const unsigned short* g = Qg
          + (size_t)(trow * 128 + (s & 15) * 8 + rl) * 256
          + h * 128 + (s >> 4) * 64 + vg * 8;
      __builtin_amdgcn_global_load_lds(
          (__attribute__((address_space(1))) void*)g,
          (__attribute__((address_space(3))) void*)(dst + s * 512), 16, 0, 0);
    }
  };
  // stage V chunk [256c][64m] at m = trow*128 + ch*64 -> dst (coalesced)
  auto stageV = [&](unsigned short* dst, int trow, int ch) {
#pragma unroll
    for (int s = wave; s < 32; s += 8) {
      const unsigned short* g = Vg + (size_t)(s * 8 + rl) * 4096
                                + trow * 128 + ch * 64 + vg * 8;
      __builtin_amdgcn_global_load_lds(
          (__attribute__((address_space(1))) void*)g,
          (__attribute__((address_space(3))) void*)(dst + s * 512), 16, 0, 0);
    }
  };

  f32x4 oacc[16] = {};
  float rsum[16] = {};
  const float C1 = 0.0625f * 1.44269504f;    // log2(e)/16
  const float C0 = -20.0f * 1.44269504f;     // -20*log2(e)

  // ---- prologue: K tile [128n][256c] (4 panels) + Q(0,h0) -> A ----
  {
    const unsigned short* Kg = kt + (size_t)(b * 4096 + n0) * 256;
#pragma unroll
    for (int s = wave; s < 64; s += 8) {
      const unsigned short* g = Kg + (size_t)((s & 15) * 8 + rl) * 256
                                + (s >> 4) * 64 + vg * 8;
      __builtin_amdgcn_global_load_lds(
          (__attribute__((address_space(1))) void*)g,
          (__attribute__((address_space(3))) void*)(Ks + s * 512), 16, 0, 0);
    }
  }
  stageQ(BufA, 0, 0);
  __syncthreads();

  // K h=0 fragments -> registers (LDS read ONCE; panels 0,1 unused after)
  bfx8 kfrag[16];                            // [(i*2+p2)*2+kk]
#pragma unroll
  for (int i = 0; i < 4; ++i)
#pragma unroll
    for (int p2 = 0; p2 < 2; ++p2)
#pragma unroll
      for (int kk = 0; kk < 2; ++kk)
        kfrag[(i * 2 + p2) * 2 + kk] = *(const bfx8*)(Ks + p2 * 8192
            + (rn * 64 + i * 16 + lr) * 64 + (((quad + kk * 4) ^ sw) << 3));

#pragma unroll 1
  for (int t = 0; t < 16; ++t) {
    f32x4 sacc[8] = {};

    // compute O chunk ch from staged V buffer Vb (P from Ps panel ch)
    auto computeO = [&](const unsigned short* Vb, int ch) {
      __builtin_amdgcn_s_setprio(1);
#pragma unroll
      for (int kk = 0; kk < 2; ++kk) {
        const int kv = kk * 4;
        bfx8 ap[4], bvf[4];
#pragma unroll
        for (int i = 0; i < 4; ++i)
          ap[i] = *(const bfx8*)(Ps + ch * 8192
                   + (rn * 64 + i * 16 + lr) * 64 + (((quad + kv) ^ sw) << 3));
#pragma unroll
        for (int j = 0; j < 4; ++j)
          bvf[j] = *(const bfx8*)(Vb
                   + (cw * 64 + j * 16 + lr) * 64 + (((quad + kv) ^ sw) << 3));
#pragma unroll
        for (int i = 0; i < 4; ++i)
#pragma unroll
          for (int j = 0; j < 4; ++j)
            oacc[i * 4 + j] = __builtin_amdgcn_mfma_f32_16x16x32_bf16(
                ap[i], bvf[j], oacc[i * 4 + j], 0, 0, 0);
      }
      __builtin_amdgcn_s_setprio(0);
    };

    // ---- p0: prefetch Q(t,h1)->B; S-h0 (K from kfrag, Q from A) ----
    stageQ(BufB, t, 1);
    __builtin_amdgcn_s_setprio(1);
#pragma unroll
    for (int p2 = 0; p2 < 2; ++p2)
#pragma unroll
      for (int kk = 0; kk < 2; ++kk) {
        const int kv = kk * 4;
        bfx8 bq[2];
#pragma unroll
        for (int j = 0; j < 2; ++j)
          bq[j] = *(const bfx8*)(BufA + p2 * 8192
                   + (cw * 32 + j * 16 + lr) * 64 + (((quad + kv) ^ sw) << 3));
#pragma unroll
        for (int i = 0; i < 4; ++i)
#pragma unroll
          for (int j = 0; j < 2; ++j)
            sacc[i * 2 + j] = __builtin_amdgcn_mfma_f32_16x16x32_bf16(
                kfrag[(i * 2 + p2) * 2 + kk], bq[j], sacc[i * 2 + j], 0, 0, 0);
      }
    __builtin_amdgcn_s_setprio(0);
    __syncthreads();

    // ---- p1: prefetch V(t,0)->A; S-h1 (K LDS panels 2,3; Q from B); exp --
    stageV(BufA, t, 0);
    __builtin_amdgcn_s_setprio(1);
#pragma unroll
    for (int p2 = 0; p2 < 2; ++p2)
#pragma unroll
      for (int kk = 0; kk < 2; ++kk) {
        const int kv = kk * 4;
        bfx8 af[4], bq[2];
#pragma unroll
        for (int i = 0; i < 4; ++i)
          af[i] = *(const bfx8*)(Ks + (2 + p2) * 8192
                   + (rn * 64 + i * 16 + lr) * 64 + (((quad + kv) ^ sw) << 3));
#pragma unroll
        for (int j = 0; j < 2; ++j)
          bq[j] = *(const bfx8*)(BufB + p2 * 8192
                   + (cw * 32 + j * 16 + lr) * 64 + (((quad + kv) ^ sw) << 3));
#pragma unroll
        for (int i = 0; i < 4; ++i)
#pragma unroll
          for (int j = 0; j < 2; ++j)
            sacc[i * 2 + j] = __builtin_amdgcn_mfma_f32_16x16x32_bf16(
                af[i], bq[j], sacc[i * 2 + j], 0, 0, 0);
      }
    __builtin_amdgcn_s_setprio(0);
    // exp + P write to LDS (both panels), swizzled like gemm_core
#pragma unroll
    for (int i = 0; i < 4; ++i)
#pragma unroll
      for (int j = 0; j < 2; ++j)
#pragma unroll
        for (int r = 0; r < 4; ++r) {
          float p = __builtin_amdgcn_exp2f(fmaf(sacc[i * 2 + j][r], C1, C0));
          rsum[i * 4 + r] += p;
          const int row = rn * 64 + i * 16 + quad * 4 + r;
          const int cvec = cw * 4 + j * 2 + (lr >> 3);   // m_col>>3
          Ps[(cvec >> 3) * 8192 + row * 64
             + (((cvec & 7) ^ (row & 7)) << 3) + (lr & 7)] = f2s(p);
        }
    __syncthreads();

    // ---- p2: prefetch V(t,1)->B; O-ch0 from A (=V0) ----
    stageV(BufB, t, 1);
    computeO(BufA, 0);
    __syncthreads();

    // ---- p3: prefetch Q(t+1,0)->A; O-ch1 from B (=V1) ----
    if (t < 15) stageQ(BufA, t + 1, 0);
    computeO(BufB, 1);
    __syncthreads();
  }

  // ---- epilogue: fp32 partials + lsum atomics ----
  float* op = opart + ((size_t)(ms * 4 + b) * 4096 + n0) * 256;
#pragma unroll
  for (int i = 0; i < 4; ++i)
#pragma unroll
    for (int j = 0; j < 4; ++j)
#pragma unroll
      for (int r = 0; r < 4; ++r) {
        const int row = rn * 64 + i * 16 + quad * 4 + r;
        const int col = cw * 64 + j * 16 + lr;
        op[(size_t)row * 256 + col] = oacc[i * 4 + j][r];
      }
  float* l = lsum + b * 4096 + n0;
#pragma unroll
  for (int i = 0; i < 4; ++i)
#pragma unroll
    for (int r = 0; r < 4; ++r) {
      float rs = rsum[i * 4 + r];
      rs += __shfl_down(rs, 8, 16);
      rs += __shfl_down(rs, 4, 16);
      rs += __shfl_down(rs, 2, 16);
      rs += __shfl_down(rs, 1, 16);
      if (lr == 0) atomicAdd(&l[rn * 64 + i * 16 + quad * 4 + r], rs);
    }
}

// ---------------------------------------------------------------------------
// k_red: ctx[b,n][c] = (opart[0][b,n][c] + opart[1][b,n][c]) / lsum[b][n]
// grid 16384 (b*4096+n) x 256 (c). Coalesced.
// ---------------------------------------------------------------------------
__global__ __launch_bounds__(256) void k_red(
    const float* __restrict__ opart, const float* __restrict__ lsum,
    unsigned short* __restrict__ ctx)
{
  const int g = blockIdx.x, c = threadIdx.x;     // g = b*4096 + n
  const float s = opart[(size_t)g * 256 + c]
                + opart[((size_t)g + 16384) * 256 + c];
  ctx[(size_t)g * 256 + c] = f2s(s / lsum[g]);
}

// ---------------------------------------------------------------------------
// Out: out[b][o][n] = sum_cv wW[o][cv] ctx[b,n][cv] + bW[o] + x[b][o][n]
// ---------------------------------------------------------------------------
__global__ __launch_bounds__(256) void k_out(
    const unsigned short* __restrict__ wWb, const float* __restrict__ bW,
    const unsigned short* __restrict__ ctx, const float* __restrict__ x,
    float* __restrict__ out)
{
  __shared__ __align__(16) unsigned short As[128 * 64], Bs[128 * 64];
  f32x4 acc[16] = {};
  const int b = blockIdx.z, n0 = blockIdx.x * 128, o0 = blockIdx.y * 128;
  gemm_core_async<128, 128, 64>(wWb + (size_t)o0 * 256, 256,
                                ctx + ((size_t)b * 4096 + n0) * 256, 256, 256,
                                As, Bs, acc);
  const int lane = threadIdx.x & 63, wave = threadIdx.x >> 6;
  const int lr = lane & 15, quad = lane >> 4;
  const int wm = (wave >> 1) * 64, wn = (wave & 1) * 64;
#pragma unroll
  for (int i = 0; i < 4; ++i)
#pragma unroll
    for (int j = 0; j < 4; ++j)
#pragma unroll
      for (int r = 0; r < 4; ++r) {
        int row = wm + i * 16 + quad * 4 + r, col = wn + j * 16 + lr;
        size_t idx = ((size_t)b * 512 + o0 + row) * 4096 + n0 + col;
        out[idx] = acc[i * 4 + j][r] + bW[o0 + row] + x[idx];
      }
}

// ---------------------------------------------------------------------------
extern "C" void kernel_launch(void* const* d_in, const int* in_sizes, int n_in,
                              void* d_out, int out_size, void* d_ws, size_t ws_size,
                              hipStream_t stream)
{
  const float* x     = (const float*)d_in[0];
  const float* wq    = (const float*)d_in[1];
  // d_in[2] = bq: cancelled exactly by BN mean-subtraction
  const float* gq    = (const float*)d_in[3];
  const float* betaq = (const float*)d_in[4];
  const float* wk    = (const float*)d_in[5];
  // d_in[6] = bk: cancelled
  const float* gk    = (const float*)d_in[7];
  const float* betak = (const float*)d_in[8];
  const float* wv    = (const float*)d_in[9];
  const float* bv    = (const float*)d_in[10];
  const float* wW    = (const float*)d_in[11];
  const float* bW    = (const float*)d_in[12];
  float* out = (float*)d_out;

  // workspace layout (ws_size = 256 MiB)
  char* ws = (char*)d_ws;
  unsigned short* qt   = (unsigned short*)(ws);              //  8 MiB [4*4096,256]
  unsigned short* kt   = (unsigned short*)(ws + 8388608);    //  8 MiB
  unsigned short* v    = (unsigned short*)(ws + 16777216);   //  8 MiB [4,256,4096]
  unsigned short* ctx  = (unsigned short*)(ws + 25165824);   //  8 MiB [4*4096,256]
  unsigned short* wqk  = (unsigned short*)(ws + 33554432);   // 512 KiB [512,512]
  unsigned short* wvb  = (unsigned short*)(ws + 34078720);   // 256 KiB [256,512]
  unsigned short* wWb  = (unsigned short*)(ws + 34340864);   // 256 KiB [512,256]
  float*          stat = (float*)         (ws + 34603008);   //   4 KiB
  float*          lsum = (float*)         (ws + 34607104);   //  64 KiB [4][4096]
  float*          opart= (float*)         (ws + 35651584);   // 32 MiB [2,4,4096,256] fp32
  unsigned short* xt   = (unsigned short*)(ws + 35651584);   // 16 MiB, aliases opart
  unsigned short* zt   = (unsigned short*)(ws + 52428800);   // 16 MiB, aliases opart
                                                             // (xt dead after k_qkv,
                                                             //  zt dead after k_bnrelu,
                                                             //  both before k_att)

  (void)hipMemsetAsync(stat, 0, 69632, stream);  // stat (4K) + lsum (64K)
  k_pre   <<<3072, 256, 0, stream>>>(x, xt, wq, wk, wv, wW, wqk, wvb, wWb);
  k_qkv   <<<dim3(32, 6, 4), 256, 0, stream>>>(xt, wqk, wvb, bv, zt, v, stat);
  k_bnrelu<<<1024, 256, 0, stream>>>(zt, stat, gq, betaq, gk, betak, qt, kt);
  k_att   <<<dim3(2, 32, 4), 512, 0, stream>>>(qt, kt, v, opart, lsum);
  k_red   <<<16384, 256, 0, stream>>>(opart, lsum, ctx);
  k_out   <<<dim3(32, 4, 4), 256, 0, stream>>>(wWb, bW, ctx, x, out);
}

// Round 8
// 248.403 us; speedup vs baseline: 1.6235x; 1.5481x over previous
//
#include <hip/hip_runtime.h>

typedef __attribute__((ext_vector_type(8))) __bf16 bfx8;
typedef __attribute__((ext_vector_type(4))) float f32x4;

__device__ __forceinline__ float s2f(unsigned short s) {
  return __uint_as_float((unsigned int)s << 16);
}
// round-half-up bf16 convert (2 VALU ops; tie-only difference vs RNE)
__device__ __forceinline__ unsigned short f2s(float f) {
  return (unsigned short)((__float_as_uint(f) + 0x8000u) >> 16);
}

// ---------------------------------------------------------------------------
// Async MFMA GEMM core (global_load_lds staging, XOR-swizzled; R5-verified:
// SQ_LDS_BANK_CONFLICT == 0). Both operands [row][k] k-contiguous.
// D[m][n] = sum_k Ag[m][k]*Bg[n][k]. 256 thr = 4 waves 2x2.
// ---------------------------------------------------------------------------
template<int BM, int BN, int BK>
__device__ __forceinline__ void gemm_core_async(
    const unsigned short* __restrict__ Ag, int lda,
    const unsigned short* __restrict__ Bg, int ldb, int K,
    unsigned short* As, unsigned short* Bs, f32x4* acc)
{
  static_assert(BK == 64, "BK must be 64 (128B rows)");
  constexpr int WM = BM / 2, WN = BN / 2;
  constexpr int MT = WM / 16, NT = WN / 16;
  constexpr int SA = BM / 8, SB = BN / 8;   // 1024B segments per tile
  const int tid = threadIdx.x;
  const int lane = tid & 63, wave = tid >> 6;
  const int lr = lane & 15, quad = lane >> 4;
  const int sw = lr & 7;
  const int rl = lane >> 3;                  // row within segment (0..7)
  const int vg = (lane & 7) ^ rl;            // swizzled global vec index
  const int wm = (wave >> 1) * WM, wn = (wave & 1) * WN;

  for (int k0 = 0; k0 < K; k0 += BK) {
#pragma unroll
    for (int s = wave; s < SA; s += 4) {
      const unsigned short* g = Ag + (size_t)(s * 8 + rl) * lda + k0 + vg * 8;
      __builtin_amdgcn_global_load_lds(
          (__attribute__((address_space(1))) void*)g,
          (__attribute__((address_space(3))) void*)(As + s * 512), 16, 0, 0);
    }
#pragma unroll
    for (int s = wave; s < SB; s += 4) {
      const unsigned short* g = Bg + (size_t)(s * 8 + rl) * ldb + k0 + vg * 8;
      __builtin_amdgcn_global_load_lds(
          (__attribute__((address_space(1))) void*)g,
          (__attribute__((address_space(3))) void*)(Bs + s * 512), 16, 0, 0);
    }
    __syncthreads();
#pragma unroll
    for (int kk = 0; kk < BK; kk += 32) {
      const int kv = kk >> 3;                // 0 or 4
      bfx8 af[MT], bfr[NT];
#pragma unroll
      for (int i = 0; i < MT; ++i)
        af[i] = *(const bfx8*)(As + (wm + i * 16 + lr) * BK
                               + (((quad + kv) ^ sw) << 3));
#pragma unroll
      for (int j = 0; j < NT; ++j)
        bfr[j] = *(const bfx8*)(Bs + (wn + j * 16 + lr) * BK
                                + (((quad + kv) ^ sw) << 3));
#pragma unroll
      for (int i = 0; i < MT; ++i)
#pragma unroll
        for (int j = 0; j < NT; ++j)
          acc[i * NT + j] = __builtin_amdgcn_mfma_f32_16x16x32_bf16(
              af[i], bfr[j], acc[i * NT + j], 0, 0, 0);
    }
    __syncthreads();
  }
}

// ---------------------------------------------------------------------------
// k_pre: fused x transpose (fp32 [4][512][4096] -> bf16 x_t [4][4096][512],
// blocks 0..2047) and weight converts (blocks 2048..3071).
// ---------------------------------------------------------------------------
__global__ __launch_bounds__(256) void k_pre(
    const float* __restrict__ x, unsigned short* __restrict__ xt,
    const float* __restrict__ wq, const float* __restrict__ wk,
    const float* __restrict__ wv, const float* __restrict__ wW,
    unsigned short* __restrict__ wqk, unsigned short* __restrict__ wvb,
    unsigned short* __restrict__ wWb)
{
  const int bid = blockIdx.x, tid = threadIdx.x;
  if (bid < 2048) {
    __shared__ float t[64][65];
    const int b = bid >> 9, c0 = ((bid >> 6) & 7) * 64, n0 = (bid & 63) * 64;
    const float* xb = x + ((size_t)b << 21);
    const int hi = tid >> 6, lo = tid & 63;
#pragma unroll
    for (int p = 0; p < 16; ++p)
      t[hi + p * 4][lo] = xb[(size_t)(c0 + hi + p * 4) * 4096 + n0 + lo];
    __syncthreads();
    unsigned short* xtb = xt + ((size_t)b << 21);
#pragma unroll
    for (int p = 0; p < 16; ++p)
      xtb[(size_t)(n0 + hi + p * 4) * 512 + c0 + lo] = f2s(t[lo][hi + p * 4]);
  } else {
    int i = (bid - 2048) * 256 + tid;              // i < 262144
    wqk[i] = f2s(i < 131072 ? wq[i] : wk[i - 131072]);
    if (i < 131072) { wvb[i] = f2s(wv[i]); wWb[i] = f2s(wW[i]); }
  }
}

// ---------------------------------------------------------------------------
// k_qkv: fused QK GEMM (+fp32 BN stats partials in epilogue) and V GEMM.
// ---------------------------------------------------------------------------
__global__ __launch_bounds__(256) void k_qkv(
    const unsigned short* __restrict__ xt, const unsigned short* __restrict__ wqk,
    const unsigned short* __restrict__ wvb, const float* __restrict__ bv,
    unsigned short* __restrict__ zt, unsigned short* __restrict__ v,
    float* __restrict__ stat)
{
  __shared__ __align__(16) unsigned short As[128 * 64], Bs[128 * 64];
  f32x4 acc[16] = {};
  const int b = blockIdx.z, n0 = blockIdx.x * 128, t = blockIdx.y;
  const int lane = threadIdx.x & 63, wave = threadIdx.x >> 6;
  const int lr = lane & 15, quad = lane >> 4;
  const int wm = (wave >> 1) * 64, wn = (wave & 1) * 64;

  if (t < 4) {
    const int o0 = t * 128;
    gemm_core_async<128, 128, 64>(xt + ((size_t)b * 4096 + n0) * 512, 512,
                                  wqk + (size_t)o0 * 512, 512, 512, As, Bs, acc);
    float s[4] = {}, ss[4] = {};
#pragma unroll
    for (int i = 0; i < 4; ++i)
#pragma unroll
      for (int j = 0; j < 4; ++j)
#pragma unroll
        for (int r = 0; r < 4; ++r) {
          float a = acc[i * 4 + j][r];
          int row = wm + i * 16 + quad * 4 + r, col = wn + j * 16 + lr;
          zt[((size_t)b * 4096 + n0 + row) * 512 + o0 + col] = f2s(a);
          s[j] += a; ss[j] += a * a;
        }
#pragma unroll
    for (int j = 0; j < 4; ++j) {
      s[j]  += __shfl_down(s[j], 32, 64);  s[j]  += __shfl_down(s[j], 16, 64);
      ss[j] += __shfl_down(ss[j], 32, 64); ss[j] += __shfl_down(ss[j], 16, 64);
      if (quad == 0) {
        int o = o0 + wn + j * 16 + lr;
        atomicAdd(&stat[o * 2], s[j]);
        atomicAdd(&stat[o * 2 + 1], ss[j]);
      }
    }
  } else {
    const int cv0 = (t - 4) * 128;
    gemm_core_async<128, 128, 64>(wvb + (size_t)cv0 * 512, 512,
                                  xt + ((size_t)b * 4096 + n0) * 512, 512, 512,
                                  As, Bs, acc);
#pragma unroll
    for (int i = 0; i < 4; ++i)
#pragma unroll
      for (int j = 0; j < 4; ++j)
#pragma unroll
        for (int r = 0; r < 4; ++r) {
          int row = wm + i * 16 + quad * 4 + r, col = wn + j * 16 + lr;
          v[((size_t)b * 256 + cv0 + row) * 4096 + n0 + col] =
              f2s(acc[i * 4 + j][r] + bv[cv0 + row]);
        }
  }
}

// ---------------------------------------------------------------------------
// BN+ReLU: q_t[n][c] / k_t[n][c] bf16 from z_t columns.
// ---------------------------------------------------------------------------
__global__ __launch_bounds__(256) void k_bnrelu(
    const unsigned short* __restrict__ zt, const float* __restrict__ stats_raw,
    const float* __restrict__ gq, const float* __restrict__ betaq,
    const float* __restrict__ gk, const float* __restrict__ betak,
    unsigned short* __restrict__ qt, unsigned short* __restrict__ kt)
{
  const int t = threadIdx.x;
  const float mA = stats_raw[t * 2] * (1.f / 16384.f);
  const float vA = stats_raw[t * 2 + 1] * (1.f / 16384.f) - mA * mA;
  const float scA = rsqrtf(vA + 1e-5f) * gq[t], beA = betaq[t];
  const float mB = stats_raw[(t + 256) * 2] * (1.f / 16384.f);
  const float vB = stats_raw[(t + 256) * 2 + 1] * (1.f / 16384.f) - mB * mB;
  const float scB = rsqrtf(vB + 1e-5f) * gk[t], beB = betak[t];
  const int r0 = blockIdx.x * 16;
  for (int r = r0; r < r0 + 16; ++r) {
    float a = s2f(zt[(size_t)r * 512 + t]);
    qt[(size_t)r * 256 + t] = f2s(fmaxf((a - mA) * scA + beA, 0.f));
    float c = s2f(zt[(size_t)r * 512 + t + 256]);
    kt[(size_t)r * 256 + t] = f2s(fmaxf((c - mB) * scB + beB, 0.f));
  }
}

// ---------------------------------------------------------------------------
// k_att: fused flash-style attention core (P stays in LDS; fixed-shift
// softmax exp(s/16-20), exact since q,k>=0).
// R8 = exact R4 structure (88.9 us verified; R5-R7 all regressed: V-gather
// is transaction-bound, kfrag structurally spills at 128-VGPR cap) plus the
// ONLY safe addition: T5 s_setprio(1/0) around MFMA clusters (2 SALU instrs,
// no memory/register impact; isolated A/B this round).
// Phases per m-step (4 barriers), staging issued BEFORE compute:
//   p0: stage Q(t,h1)->B  | S-h0 from A   | sync
//   p1: stage V(t,0) ->A  | S-h1 from B, exp+P->Ps | sync
//   p2: stage V(t,1) ->B  | O-ch0 from A  | sync
//   p3: stage Q(t+1,0)->A | O-ch1 from B  | sync
// LDS 160 KiB: Ks 64K (K tile, staged once) + BufA/BufB 32K + Ps 32K.
// 512 thr (8 waves 2(n) x 4(m|c)), grid (2 ms, 32 n, 4 b).
// ---------------------------------------------------------------------------
__global__ __launch_bounds__(512, 2) void k_att(
    const unsigned short* __restrict__ qt, const unsigned short* __restrict__ kt,
    const unsigned short* __restrict__ v, float* __restrict__ opart,
    float* __restrict__ lsum)
{
  __shared__ __align__(16) unsigned short Ks[4 * 8192];
  __shared__ __align__(16) unsigned short BufA[2 * 8192];
  __shared__ __align__(16) unsigned short BufB[2 * 8192];
  __shared__ __align__(16) unsigned short Ps[2 * 8192];

  const int tid = threadIdx.x;
  const int lane = tid & 63, wave = tid >> 6;
  const int lr = lane & 15, quad = lane >> 4;
  const int sw = lr & 7;
  const int rl = lane >> 3;                  // row within 8-row segment
  const int vg = (lane & 7) ^ rl;            // swizzled global vec index
  const int rn = wave >> 2, cw = wave & 3;   // wave grid 2(n) x 4(m or c)

  const int ms = blockIdx.x, n0 = blockIdx.y * 128, b = blockIdx.z;

  const unsigned short* Qg = qt + (size_t)(b * 4096 + ms * 2048) * 256;
  const unsigned short* Vg = v + (size_t)(b * 256) * 4096 + ms * 2048;

  // stage Q panel [128m][128c] (t-row, c-half h) -> dst (32 segs of 1024B)
  auto stageQ = [&](unsigned short* dst, int trow, int h) {
#pragma unroll
    for (int s = wave; s < 32; s += 8) {
      const unsigned short* g = Qg
          + (size_t)(trow * 128 + (s & 15) * 8 + rl) * 256
          + h * 128 + (s >> 4) * 64 + vg * 8;
      __builtin_amdgcn_global_load_lds(
          (__attribute__((address_space(1))) void*)g,
          (__attribute__((address_space(3))) void*)(dst + s * 512), 16, 0, 0);
    }
  };
  // stage V chunk [256c][64m] at m = trow*128 + ch*64 -> dst (coalesced)
  auto stageV = [&](unsigned short* dst, int trow, int ch) {
#pragma unroll
    for (int s = wave; s < 32; s += 8) {
      const unsigned short* g = Vg + (size_t)(s * 8 + rl) * 4096
                                + trow * 128 + ch * 64 + vg * 8;
      __builtin_amdgcn_global_load_lds(
          (__attribute__((address_space(1))) void*)g,
          (__attribute__((address_space(3))) void*)(dst + s * 512), 16, 0, 0);
    }
  };

  f32x4 oacc[16] = {};
  float rsum[16] = {};
  const float C1 = 0.0625f * 1.44269504f;    // log2(e)/16
  const float C0 = -20.0f * 1.44269504f;     // -20*log2(e)

  // ---- prologue: K tile [128n][256c] (4 panels) + Q(0,h0) -> A ----
  {
    const unsigned short* Kg = kt + (size_t)(b * 4096 + n0) * 256;
#pragma unroll
    for (int s = wave; s < 64; s += 8) {
      const unsigned short* g = Kg + (size_t)((s & 15) * 8 + rl) * 256
                                + (s >> 4) * 64 + vg * 8;
      __builtin_amdgcn_global_load_lds(
          (__attribute__((address_space(1))) void*)g,
          (__attribute__((address_space(3))) void*)(Ks + s * 512), 16, 0, 0);
    }
  }
  stageQ(BufA, 0, 0);
  __syncthreads();

#pragma unroll 1
  for (int t = 0; t < 16; ++t) {
    f32x4 sacc[8] = {};

    // compute S half h from staged Q buffer Qb into sacc
    auto computeS = [&](const unsigned short* Qb, int h) {
      __builtin_amdgcn_s_setprio(1);
#pragma unroll
      for (int p2 = 0; p2 < 2; ++p2)
#pragma unroll
        for (int kk = 0; kk < 2; ++kk) {
          const int kv = kk * 4;
          bfx8 af[4], bq[2];
#pragma unroll
          for (int i = 0; i < 4; ++i)
            af[i] = *(const bfx8*)(Ks + (h * 2 + p2) * 8192
                     + (rn * 64 + i * 16 + lr) * 64 + (((quad + kv) ^ sw) << 3));
#pragma unroll
          for (int j = 0; j < 2; ++j)
            bq[j] = *(const bfx8*)(Qb + p2 * 8192
                     + (cw * 32 + j * 16 + lr) * 64 + (((quad + kv) ^ sw) << 3));
#pragma unroll
          for (int i = 0; i < 4; ++i)
#pragma unroll
            for (int j = 0; j < 2; ++j)
              sacc[i * 2 + j] = __builtin_amdgcn_mfma_f32_16x16x32_bf16(
                  af[i], bq[j], sacc[i * 2 + j], 0, 0, 0);
        }
      __builtin_amdgcn_s_setprio(0);
    };
    // compute O chunk ch from staged V buffer Vb (P from Ps panel ch)
    auto computeO = [&](const unsigned short* Vb, int ch) {
      __builtin_amdgcn_s_setprio(1);
#pragma unroll
      for (int kk = 0; kk < 2; ++kk) {
        const int kv = kk * 4;
        bfx8 ap[4], bvf[4];
#pragma unroll
        for (int i = 0; i < 4; ++i)
          ap[i] = *(const bfx8*)(Ps + ch * 8192
                   + (rn * 64 + i * 16 + lr) * 64 + (((quad + kv) ^ sw) << 3));
#pragma unroll
        for (int j = 0; j < 4; ++j)
          bvf[j] = *(const bfx8*)(Vb
                   + (cw * 64 + j * 16 + lr) * 64 + (((quad + kv) ^ sw) << 3));
#pragma unroll
        for (int i = 0; i < 4; ++i)
#pragma unroll
          for (int j = 0; j < 4; ++j)
            oacc[i * 4 + j] = __builtin_amdgcn_mfma_f32_16x16x32_bf16(
                ap[i], bvf[j], oacc[i * 4 + j], 0, 0, 0);
      }
      __builtin_amdgcn_s_setprio(0);
    };

    // ---- p0: prefetch Q(t,h1)->B; S-h0 from A ----
    stageQ(BufB, t, 1);
    computeS(BufA, 0);
    __syncthreads();

    // ---- p1: prefetch V(t,0)->A; S-h1 from B; exp + P->Ps ----
    stageV(BufA, t, 0);
    computeS(BufB, 1);
#pragma unroll
    for (int i = 0; i < 4; ++i)
#pragma unroll
      for (int j = 0; j < 2; ++j)
#pragma unroll
        for (int r = 0; r < 4; ++r) {
          float p = __builtin_amdgcn_exp2f(fmaf(sacc[i * 2 + j][r], C1, C0));
          rsum[i * 4 + r] += p;
          const int row = rn * 64 + i * 16 + quad * 4 + r;
          const int cvec = cw * 4 + j * 2 + (lr >> 3);   // m_col>>3
          Ps[(cvec >> 3) * 8192 + row * 64
             + (((cvec & 7) ^ (row & 7)) << 3) + (lr & 7)] = f2s(p);
        }
    __syncthreads();

    // ---- p2: prefetch V(t,1)->B; O-ch0 from A (=V0) ----
    stageV(BufB, t, 1);
    computeO(BufA, 0);
    __syncthreads();

    // ---- p3: prefetch Q(t+1,0)->A; O-ch1 from B (=V1) ----
    if (t < 15) stageQ(BufA, t + 1, 0);
    computeO(BufB, 1);
    __syncthreads();
  }

  // ---- epilogue: fp32 partials + lsum atomics ----
  float* op = opart + ((size_t)(ms * 4 + b) * 4096 + n0) * 256;
#pragma unroll
  for (int i = 0; i < 4; ++i)
#pragma unroll
    for (int j = 0; j < 4; ++j)
#pragma unroll
      for (int r = 0; r < 4; ++r) {
        const int row = rn * 64 + i * 16 + quad * 4 + r;
        const int col = cw * 64 + j * 16 + lr;
        op[(size_t)row * 256 + col] = oacc[i * 4 + j][r];
      }
  float* l = lsum + b * 4096 + n0;
#pragma unroll
  for (int i = 0; i < 4; ++i)
#pragma unroll
    for (int r = 0; r < 4; ++r) {
      float rs = rsum[i * 4 + r];
      rs += __shfl_down(rs, 8, 16);
      rs += __shfl_down(rs, 4, 16);
      rs += __shfl_down(rs, 2, 16);
      rs += __shfl_down(rs, 1, 16);
      if (lr == 0) atomicAdd(&l[rn * 64 + i * 16 + quad * 4 + r], rs);
    }
}

// ---------------------------------------------------------------------------
// k_red: ctx[b,n][c] = (opart[0][b,n][c] + opart[1][b,n][c]) / lsum[b][n]
// grid 16384 (b*4096+n) x 256 (c). Coalesced.
// ---------------------------------------------------------------------------
__global__ __launch_bounds__(256) void k_red(
    const float* __restrict__ opart, const float* __restrict__ lsum,
    unsigned short* __restrict__ ctx)
{
  const int g = blockIdx.x, c = threadIdx.x;     // g = b*4096 + n
  const float s = opart[(size_t)g * 256 + c]
                + opart[((size_t)g + 16384) * 256 + c];
  ctx[(size_t)g * 256 + c] = f2s(s / lsum[g]);
}

// ---------------------------------------------------------------------------
// Out: out[b][o][n] = sum_cv wW[o][cv] ctx[b,n][cv] + bW[o] + x[b][o][n]
// ---------------------------------------------------------------------------
__global__ __launch_bounds__(256) void k_out(
    const unsigned short* __restrict__ wWb, const float* __restrict__ bW,
    const unsigned short* __restrict__ ctx, const float* __restrict__ x,
    float* __restrict__ out)
{
  __shared__ __align__(16) unsigned short As[128 * 64], Bs[128 * 64];
  f32x4 acc[16] = {};
  const int b = blockIdx.z, n0 = blockIdx.x * 128, o0 = blockIdx.y * 128;
  gemm_core_async<128, 128, 64>(wWb + (size_t)o0 * 256, 256,
                                ctx + ((size_t)b * 4096 + n0) * 256, 256, 256,
                                As, Bs, acc);
  const int lane = threadIdx.x & 63, wave = threadIdx.x >> 6;
  const int lr = lane & 15, quad = lane >> 4;
  const int wm = (wave >> 1) * 64, wn = (wave & 1) * 64;
#pragma unroll
  for (int i = 0; i < 4; ++i)
#pragma unroll
    for (int j = 0; j < 4; ++j)
#pragma unroll
      for (int r = 0; r < 4; ++r) {
        int row = wm + i * 16 + quad * 4 + r, col = wn + j * 16 + lr;
        size_t idx = ((size_t)b * 512 + o0 + row) * 4096 + n0 + col;
        out[idx] = acc[i * 4 + j][r] + bW[o0 + row] + x[idx];
      }
}

// ---------------------------------------------------------------------------
extern "C" void kernel_launch(void* const* d_in, const int* in_sizes, int n_in,
                              void* d_out, int out_size, void* d_ws, size_t ws_size,
                              hipStream_t stream)
{
  const float* x     = (const float*)d_in[0];
  const float* wq    = (const float*)d_in[1];
  // d_in[2] = bq: cancelled exactly by BN mean-subtraction
  const float* gq    = (const float*)d_in[3];
  const float* betaq = (const float*)d_in[4];
  const float* wk    = (const float*)d_in[5];
  // d_in[6] = bk: cancelled
  const float* gk    = (const float*)d_in[7];
  const float* betak = (const float*)d_in[8];
  const float* wv    = (const float*)d_in[9];
  const float* bv    = (const float*)d_in[10];
  const float* wW    = (const float*)d_in[11];
  const float* bW    = (const float*)d_in[12];
  float* out = (float*)d_out;

  // workspace layout (ws_size = 256 MiB)
  char* ws = (char*)d_ws;
  unsigned short* qt   = (unsigned short*)(ws);              //  8 MiB [4*4096,256]
  unsigned short* kt   = (unsigned short*)(ws + 8388608);    //  8 MiB
  unsigned short* v    = (unsigned short*)(ws + 16777216);   //  8 MiB [4,256,4096]
  unsigned short* ctx  = (unsigned short*)(ws + 25165824);   //  8 MiB [4*4096,256]
  unsigned short* wqk  = (unsigned short*)(ws + 33554432);   // 512 KiB [512,512]
  unsigned short* wvb  = (unsigned short*)(ws + 34078720);   // 256 KiB [256,512]
  unsigned short* wWb  = (unsigned short*)(ws + 34340864);   // 256 KiB [512,256]
  float*          stat = (float*)         (ws + 34603008);   //   4 KiB
  float*          lsum = (float*)         (ws + 34607104);   //  64 KiB [4][4096]
  float*          opart= (float*)         (ws + 35651584);   // 32 MiB [2,4,4096,256] fp32
  unsigned short* xt   = (unsigned short*)(ws + 35651584);   // 16 MiB, aliases opart
  unsigned short* zt   = (unsigned short*)(ws + 52428800);   // 16 MiB, aliases opart
                                                             // (xt dead after k_qkv,
                                                             //  zt dead after k_bnrelu,
                                                             //  both before k_att)

  (void)hipMemsetAsync(stat, 0, 69632, stream);  // stat (4K) + lsum (64K)
  k_pre   <<<3072, 256, 0, stream>>>(x, xt, wq, wk, wv, wW, wqk, wvb, wWb);
  k_qkv   <<<dim3(32, 6, 4), 256, 0, stream>>>(xt, wqk, wvb, bv, zt, v, stat);
  k_bnrelu<<<1024, 256, 0, stream>>>(zt, stat, gq, betaq, gk, betak, qt, kt);
  k_att   <<<dim3(2, 32, 4), 512, 0, stream>>>(qt, kt, v, opart, lsum);
  k_red   <<<16384, 256, 0, stream>>>(opart, lsum, ctx);
  k_out   <<<dim3(32, 4, 4), 256, 0, stream>>>(wWb, bW, ctx, x, out);
}

// Round 9
// 245.884 us; speedup vs baseline: 1.6402x; 1.0102x over previous
//
#include <hip/hip_runtime.h>

typedef __attribute__((ext_vector_type(8))) __bf16 bfx8;
typedef __attribute__((ext_vector_type(4))) float f32x4;
typedef __attribute__((ext_vector_type(4))) unsigned short us4;

__device__ __forceinline__ float s2f(unsigned short s) {
  return __uint_as_float((unsigned int)s << 16);
}
// round-half-up bf16 convert (2 VALU ops; tie-only difference vs RNE)
__device__ __forceinline__ unsigned short f2s(float f) {
  return (unsigned short)((__float_as_uint(f) + 0x8000u) >> 16);
}

// ---------------------------------------------------------------------------
// Async MFMA GEMM core (global_load_lds staging, XOR-swizzled; R5-verified:
// SQ_LDS_BANK_CONFLICT == 0). Both operands [row][k] k-contiguous.
// D[m][n] = sum_k Ag[m][k]*Bg[n][k]. 256 thr = 4 waves 2x2.
// ---------------------------------------------------------------------------
template<int BM, int BN, int BK>
__device__ __forceinline__ void gemm_core_async(
    const unsigned short* __restrict__ Ag, int lda,
    const unsigned short* __restrict__ Bg, int ldb, int K,
    unsigned short* As, unsigned short* Bs, f32x4* acc)
{
  static_assert(BK == 64, "BK must be 64 (128B rows)");
  constexpr int WM = BM / 2, WN = BN / 2;
  constexpr int MT = WM / 16, NT = WN / 16;
  constexpr int SA = BM / 8, SB = BN / 8;   // 1024B segments per tile
  const int tid = threadIdx.x;
  const int lane = tid & 63, wave = tid >> 6;
  const int lr = lane & 15, quad = lane >> 4;
  const int sw = lr & 7;
  const int rl = lane >> 3;                  // row within segment (0..7)
  const int vg = (lane & 7) ^ rl;            // swizzled global vec index
  const int wm = (wave >> 1) * WM, wn = (wave & 1) * WN;

  for (int k0 = 0; k0 < K; k0 += BK) {
#pragma unroll
    for (int s = wave; s < SA; s += 4) {
      const unsigned short* g = Ag + (size_t)(s * 8 + rl) * lda + k0 + vg * 8;
      __builtin_amdgcn_global_load_lds(
          (__attribute__((address_space(1))) void*)g,
          (__attribute__((address_space(3))) void*)(As + s * 512), 16, 0, 0);
    }
#pragma unroll
    for (int s = wave; s < SB; s += 4) {
      const unsigned short* g = Bg + (size_t)(s * 8 + rl) * ldb + k0 + vg * 8;
      __builtin_amdgcn_global_load_lds(
          (__attribute__((address_space(1))) void*)g,
          (__attribute__((address_space(3))) void*)(Bs + s * 512), 16, 0, 0);
    }
    __syncthreads();
#pragma unroll
    for (int kk = 0; kk < BK; kk += 32) {
      const int kv = kk >> 3;                // 0 or 4
      bfx8 af[MT], bfr[NT];
#pragma unroll
      for (int i = 0; i < MT; ++i)
        af[i] = *(const bfx8*)(As + (wm + i * 16 + lr) * BK
                               + (((quad + kv) ^ sw) << 3));
#pragma unroll
      for (int j = 0; j < NT; ++j)
        bfr[j] = *(const bfx8*)(Bs + (wn + j * 16 + lr) * BK
                                + (((quad + kv) ^ sw) << 3));
#pragma unroll
      for (int i = 0; i < MT; ++i)
#pragma unroll
        for (int j = 0; j < NT; ++j)
          acc[i * NT + j] = __builtin_amdgcn_mfma_f32_16x16x32_bf16(
              af[i], bfr[j], acc[i * NT + j], 0, 0, 0);
    }
    __syncthreads();
  }
}

// ---------------------------------------------------------------------------
// k_pre: fused x transpose (fp32 [4][512][4096] -> bf16 x_t [4][4096][512],
// blocks 0..2047) and weight converts (blocks 2048..3071).
// ---------------------------------------------------------------------------
__global__ __launch_bounds__(256) void k_pre(
    const float* __restrict__ x, unsigned short* __restrict__ xt,
    const float* __restrict__ wq, const float* __restrict__ wk,
    const float* __restrict__ wv, const float* __restrict__ wW,
    unsigned short* __restrict__ wqk, unsigned short* __restrict__ wvb,
    unsigned short* __restrict__ wWb)
{
  const int bid = blockIdx.x, tid = threadIdx.x;
  if (bid < 2048) {
    __shared__ float t[64][65];
    const int b = bid >> 9, c0 = ((bid >> 6) & 7) * 64, n0 = (bid & 63) * 64;
    const float* xb = x + ((size_t)b << 21);
    const int hi = tid >> 6, lo = tid & 63;
#pragma unroll
    for (int p = 0; p < 16; ++p)
      t[hi + p * 4][lo] = xb[(size_t)(c0 + hi + p * 4) * 4096 + n0 + lo];
    __syncthreads();
    unsigned short* xtb = xt + ((size_t)b << 21);
#pragma unroll
    for (int p = 0; p < 16; ++p)
      xtb[(size_t)(n0 + hi + p * 4) * 512 + c0 + lo] = f2s(t[lo][hi + p * 4]);
  } else {
    int i = (bid - 2048) * 256 + tid;              // i < 262144
    wqk[i] = f2s(i < 131072 ? wq[i] : wk[i - 131072]);
    if (i < 131072) { wvb[i] = f2s(wv[i]); wWb[i] = f2s(wW[i]); }
  }
}

// ---------------------------------------------------------------------------
// k_qkv: fused QK GEMM (+fp32 BN stats partials in epilogue) and V GEMM.
// ---------------------------------------------------------------------------
__global__ __launch_bounds__(256) void k_qkv(
    const unsigned short* __restrict__ xt, const unsigned short* __restrict__ wqk,
    const unsigned short* __restrict__ wvb, const float* __restrict__ bv,
    unsigned short* __restrict__ zt, unsigned short* __restrict__ v,
    float* __restrict__ stat)
{
  __shared__ __align__(16) unsigned short As[128 * 64], Bs[128 * 64];
  f32x4 acc[16] = {};
  const int b = blockIdx.z, n0 = blockIdx.x * 128, t = blockIdx.y;
  const int lane = threadIdx.x & 63, wave = threadIdx.x >> 6;
  const int lr = lane & 15, quad = lane >> 4;
  const int wm = (wave >> 1) * 64, wn = (wave & 1) * 64;

  if (t < 4) {
    const int o0 = t * 128;
    gemm_core_async<128, 128, 64>(xt + ((size_t)b * 4096 + n0) * 512, 512,
                                  wqk + (size_t)o0 * 512, 512, 512, As, Bs, acc);
    float s[4] = {}, ss[4] = {};
#pragma unroll
    for (int i = 0; i < 4; ++i)
#pragma unroll
      for (int j = 0; j < 4; ++j)
#pragma unroll
        for (int r = 0; r < 4; ++r) {
          float a = acc[i * 4 + j][r];
          int row = wm + i * 16 + quad * 4 + r, col = wn + j * 16 + lr;
          zt[((size_t)b * 4096 + n0 + row) * 512 + o0 + col] = f2s(a);
          s[j] += a; ss[j] += a * a;
        }
#pragma unroll
    for (int j = 0; j < 4; ++j) {
      s[j]  += __shfl_down(s[j], 32, 64);  s[j]  += __shfl_down(s[j], 16, 64);
      ss[j] += __shfl_down(ss[j], 32, 64); ss[j] += __shfl_down(ss[j], 16, 64);
      if (quad == 0) {
        int o = o0 + wn + j * 16 + lr;
        atomicAdd(&stat[o * 2], s[j]);
        atomicAdd(&stat[o * 2 + 1], ss[j]);
      }
    }
  } else {
    const int cv0 = (t - 4) * 128;
    gemm_core_async<128, 128, 64>(wvb + (size_t)cv0 * 512, 512,
                                  xt + ((size_t)b * 4096 + n0) * 512, 512, 512,
                                  As, Bs, acc);
#pragma unroll
    for (int i = 0; i < 4; ++i)
#pragma unroll
      for (int j = 0; j < 4; ++j)
#pragma unroll
        for (int r = 0; r < 4; ++r) {
          int row = wm + i * 16 + quad * 4 + r, col = wn + j * 16 + lr;
          v[((size_t)b * 256 + cv0 + row) * 4096 + n0 + col] =
              f2s(acc[i * 4 + j][r] + bv[cv0 + row]);
        }
  }
}

// ---------------------------------------------------------------------------
// BN+ReLU: q_t[n][c] / k_t[n][c] bf16 from z_t columns.
// R9: u32-vectorized (2 cols/thread; was scalar 2B/lane — half-rate, G13).
// t<128: q cols {2t,2t+1}; t>=128: k cols {2(t-128), +1}.
// ---------------------------------------------------------------------------
__global__ __launch_bounds__(256) void k_bnrelu(
    const unsigned short* __restrict__ zt, const float* __restrict__ stats_raw,
    const float* __restrict__ gq, const float* __restrict__ betaq,
    const float* __restrict__ gk, const float* __restrict__ betak,
    unsigned short* __restrict__ qt, unsigned short* __restrict__ kt)
{
  const int t = threadIdx.x;
  const int half = t >> 7;                   // 0: q, 1: k
  const int c0 = (t & 127) * 2;
  const int zc = half * 256 + c0;            // zt column of first element
  const float m0 = stats_raw[zc * 2] * (1.f / 16384.f);
  const float v0 = stats_raw[zc * 2 + 1] * (1.f / 16384.f) - m0 * m0;
  const float m1 = stats_raw[(zc + 1) * 2] * (1.f / 16384.f);
  const float v1 = stats_raw[(zc + 1) * 2 + 1] * (1.f / 16384.f) - m1 * m1;
  const float* gam = half ? gk : gq;
  const float* bet = half ? betak : betaq;
  const float sc0 = rsqrtf(v0 + 1e-5f) * gam[c0], be0 = bet[c0];
  const float sc1 = rsqrtf(v1 + 1e-5f) * gam[c0 + 1], be1 = bet[c0 + 1];
  unsigned short* outp = half ? kt : qt;
  const int r0 = blockIdx.x * 16;
  for (int r = r0; r < r0 + 16; ++r) {
    const unsigned int zz = *(const unsigned int*)(zt + (size_t)r * 512 + zc);
    const float a0 = s2f((unsigned short)zz);
    const float a1 = s2f((unsigned short)(zz >> 16));
    const unsigned int o0 = f2s(fmaxf((a0 - m0) * sc0 + be0, 0.f));
    const unsigned int o1 = f2s(fmaxf((a1 - m1) * sc1 + be1, 0.f));
    *(unsigned int*)(outp + (size_t)r * 256 + c0) = o0 | (o1 << 16);
  }
}

// ---------------------------------------------------------------------------
// k_att: fused flash-style attention core (P stays in LDS; fixed-shift
// softmax exp(s/16-20), exact since q,k>=0).
// R9 = R8 (81.0 us verified: R4 schedule + setprio) + XCD swizzle (T1):
// grid (8,32), g = ms+2b -> lin%8 == g, so all 32 blocks sharing one (b,ms)
// Q/V stream land on ONE XCD (2MB hot set < 4MB L2). R5 verified this exact
// decode functionally; isolated here on the healthy kernel.
// Phases per m-step (4 barriers), staging issued BEFORE compute:
//   p0: stage Q(t,h1)->B  | S-h0 from A   | sync
//   p1: stage V(t,0) ->A  | S-h1 from B, exp+P->Ps | sync
//   p2: stage V(t,1) ->B  | O-ch0 from A  | sync
//   p3: stage Q(t+1,0)->A | O-ch1 from B  | sync
// LDS 160 KiB: Ks 64K (K tile, staged once) + BufA/BufB 32K + Ps 32K.
// 512 thr (8 waves 2(n) x 4(m|c)).
// ---------------------------------------------------------------------------
__global__ __launch_bounds__(512, 2) void k_att(
    const unsigned short* __restrict__ qt, const unsigned short* __restrict__ kt,
    const unsigned short* __restrict__ v, float* __restrict__ opart,
    float* __restrict__ lsum)
{
  __shared__ __align__(16) unsigned short Ks[4 * 8192];
  __shared__ __align__(16) unsigned short BufA[2 * 8192];
  __shared__ __align__(16) unsigned short BufB[2 * 8192];
  __shared__ __align__(16) unsigned short Ps[2 * 8192];

  const int tid = threadIdx.x;
  const int lane = tid & 63, wave = tid >> 6;
  const int lr = lane & 15, quad = lane >> 4;
  const int sw = lr & 7;
  const int rl = lane >> 3;                  // row within 8-row segment
  const int vg = (lane & 7) ^ rl;            // swizzled global vec index
  const int rn = wave >> 2, cw = wave & 3;   // wave grid 2(n) x 4(m or c)

  const int ms = blockIdx.x & 1, b = blockIdx.x >> 1;   // g = ms+2b = XCD
  const int n0 = blockIdx.y * 128;

  const unsigned short* Qg = qt + (size_t)(b * 4096 + ms * 2048) * 256;
  const unsigned short* Vg = v + (size_t)(b * 256) * 4096 + ms * 2048;

  // stage Q panel [128m][128c] (t-row, c-half h) -> dst (32 segs of 1024B)
  auto stageQ = [&](unsigned short* dst, int trow, int h) {
#pragma unroll
    for (int s = wave; s < 32; s += 8) {
      const unsigned short* g = Qg
          + (size_t)(trow * 128 + (s & 15) * 8 + rl) * 256
          + h * 128 + (s >> 4) * 64 + vg * 8;
      __builtin_amdgcn_global_load_lds(
          (__attribute__((address_space(1))) void*)g,
          (__attribute__((address_space(3))) void*)(dst + s * 512), 16, 0, 0);
    }
  };
  // stage V chunk [256c][64m] at m = trow*128 + ch*64 -> dst (coalesced)
  auto stageV = [&](unsigned short* dst, int trow, int ch) {
#pragma unroll
    for (int s = wave; s < 32; s += 8) {
      const unsigned short* g = Vg + (size_t)(s * 8 + rl) * 4096
                                + trow * 128 + ch * 64 + vg * 8;
      __builtin_amdgcn_global_load_lds(
          (__attribute__((address_space(1))) void*)g,
          (__attribute__((address_space(3))) void*)(dst + s * 512), 16, 0, 0);
    }
  };

  f32x4 oacc[16] = {};
  float rsum[16] = {};
  const float C1 = 0.0625f * 1.44269504f;    // log2(e)/16
  const float C0 = -20.0f * 1.44269504f;     // -20*log2(e)

  // ---- prologue: K tile [128n][256c] (4 panels) + Q(0,h0) -> A ----
  {
    const unsigned short* Kg = kt + (size_t)(b * 4096 + n0) * 256;
#pragma unroll
    for (int s = wave; s < 64; s += 8) {
      const unsigned short* g = Kg + (size_t)((s & 15) * 8 + rl) * 256
                                + (s >> 4) * 64 + vg * 8;
      __builtin_amdgcn_global_load_lds(
          (__attribute__((address_space(1))) void*)g,
          (__attribute__((address_space(3))) void*)(Ks + s * 512), 16, 0, 0);
    }
  }
  stageQ(BufA, 0, 0);
  __syncthreads();

#pragma unroll 1
  for (int t = 0; t < 16; ++t) {
    f32x4 sacc[8] = {};

    // compute S half h from staged Q buffer Qb into sacc
    auto computeS = [&](const unsigned short* Qb, int h) {
      __builtin_amdgcn_s_setprio(1);
#pragma unroll
      for (int p2 = 0; p2 < 2; ++p2)
#pragma unroll
        for (int kk = 0; kk < 2; ++kk) {
          const int kv = kk * 4;
          bfx8 af[4], bq[2];
#pragma unroll
          for (int i = 0; i < 4; ++i)
            af[i] = *(const bfx8*)(Ks + (h * 2 + p2) * 8192
                     + (rn * 64 + i * 16 + lr) * 64 + (((quad + kv) ^ sw) << 3));
#pragma unroll
          for (int j = 0; j < 2; ++j)
            bq[j] = *(const bfx8*)(Qb + p2 * 8192
                     + (cw * 32 + j * 16 + lr) * 64 + (((quad + kv) ^ sw) << 3));
#pragma unroll
          for (int i = 0; i < 4; ++i)
#pragma unroll
            for (int j = 0; j < 2; ++j)
              sacc[i * 2 + j] = __builtin_amdgcn_mfma_f32_16x16x32_bf16(
                  af[i], bq[j], sacc[i * 2 + j], 0, 0, 0);
        }
      __builtin_amdgcn_s_setprio(0);
    };
    // compute O chunk ch from staged V buffer Vb (P from Ps panel ch)
    auto computeO = [&](const unsigned short* Vb, int ch) {
      __builtin_amdgcn_s_setprio(1);
#pragma unroll
      for (int kk = 0; kk < 2; ++kk) {
        const int kv = kk * 4;
        bfx8 ap[4], bvf[4];
#pragma unroll
        for (int i = 0; i < 4; ++i)
          ap[i] = *(const bfx8*)(Ps + ch * 8192
                   + (rn * 64 + i * 16 + lr) * 64 + (((quad + kv) ^ sw) << 3));
#pragma unroll
        for (int j = 0; j < 4; ++j)
          bvf[j] = *(const bfx8*)(Vb
                   + (cw * 64 + j * 16 + lr) * 64 + (((quad + kv) ^ sw) << 3));
#pragma unroll
        for (int i = 0; i < 4; ++i)
#pragma unroll
          for (int j = 0; j < 4; ++j)
            oacc[i * 4 + j] = __builtin_amdgcn_mfma_f32_16x16x32_bf16(
                ap[i], bvf[j], oacc[i * 4 + j], 0, 0, 0);
      }
      __builtin_amdgcn_s_setprio(0);
    };

    // ---- p0: prefetch Q(t,h1)->B; S-h0 from A ----
    stageQ(BufB, t, 1);
    computeS(BufA, 0);
    __syncthreads();

    // ---- p1: prefetch V(t,0)->A; S-h1 from B; exp + P->Ps ----
    stageV(BufA, t, 0);
    computeS(BufB, 1);
#pragma unroll
    for (int i = 0; i < 4; ++i)
#pragma unroll
      for (int j = 0; j < 2; ++j)
#pragma unroll
        for (int r = 0; r < 4; ++r) {
          float p = __builtin_amdgcn_exp2f(fmaf(sacc[i * 2 + j][r], C1, C0));
          rsum[i * 4 + r] += p;
          const int row = rn * 64 + i * 16 + quad * 4 + r;
          const int cvec = cw * 4 + j * 2 + (lr >> 3);   // m_col>>3
          Ps[(cvec >> 3) * 8192 + row * 64
             + (((cvec & 7) ^ (row & 7)) << 3) + (lr & 7)] = f2s(p);
        }
    __syncthreads();

    // ---- p2: prefetch V(t,1)->B; O-ch0 from A (=V0) ----
    stageV(BufB, t, 1);
    computeO(BufA, 0);
    __syncthreads();

    // ---- p3: prefetch Q(t+1,0)->A; O-ch1 from B (=V1) ----
    if (t < 15) stageQ(BufA, t + 1, 0);
    computeO(BufB, 1);
    __syncthreads();
  }

  // ---- epilogue: fp32 partials + lsum atomics ----
  float* op = opart + ((size_t)(ms * 4 + b) * 4096 + n0) * 256;
#pragma unroll
  for (int i = 0; i < 4; ++i)
#pragma unroll
    for (int j = 0; j < 4; ++j)
#pragma unroll
      for (int r = 0; r < 4; ++r) {
        const int row = rn * 64 + i * 16 + quad * 4 + r;
        const int col = cw * 64 + j * 16 + lr;
        op[(size_t)row * 256 + col] = oacc[i * 4 + j][r];
      }
  float* l = lsum + b * 4096 + n0;
#pragma unroll
  for (int i = 0; i < 4; ++i)
#pragma unroll
    for (int r = 0; r < 4; ++r) {
      float rs = rsum[i * 4 + r];
      rs += __shfl_down(rs, 8, 16);
      rs += __shfl_down(rs, 4, 16);
      rs += __shfl_down(rs, 2, 16);
      rs += __shfl_down(rs, 1, 16);
      if (lr == 0) atomicAdd(&l[rn * 64 + i * 16 + quad * 4 + r], rs);
    }
}

// ---------------------------------------------------------------------------
// k_red: ctx[b,n][c] = (opart[0][b,n][c] + opart[1][b,n][c]) / lsum[b][n]
// R9: x4-vectorized (f32x4 reads, 8B bf16 writes). grid 4096 x 256.
// ---------------------------------------------------------------------------
__global__ __launch_bounds__(256) void k_red(
    const float* __restrict__ opart, const float* __restrict__ lsum,
    unsigned short* __restrict__ ctx)
{
  const int q = blockIdx.x * 256 + threadIdx.x;  // quad index < 1048576
  const int g = q >> 6, c4 = (q & 63) * 4;       // g = b*4096+n
  const f32x4 a = *(const f32x4*)(opart + (size_t)g * 256 + c4);
  const f32x4 b2 = *(const f32x4*)(opart + ((size_t)g + 16384) * 256 + c4);
  const float l = lsum[g];
  us4 o;
#pragma unroll
  for (int e = 0; e < 4; ++e) o[e] = f2s((a[e] + b2[e]) / l);
  *(us4*)(ctx + (size_t)g * 256 + c4) = o;
}

// ---------------------------------------------------------------------------
// Out: out[b][o][n] = sum_cv wW[o][cv] ctx[b,n][cv] + bW[o] + x[b][o][n]
// ---------------------------------------------------------------------------
__global__ __launch_bounds__(256) void k_out(
    const unsigned short* __restrict__ wWb, const float* __restrict__ bW,
    const unsigned short* __restrict__ ctx, const float* __restrict__ x,
    float* __restrict__ out)
{
  __shared__ __align__(16) unsigned short As[128 * 64], Bs[128 * 64];
  f32x4 acc[16] = {};
  const int b = blockIdx.z, n0 = blockIdx.x * 128, o0 = blockIdx.y * 128;
  gemm_core_async<128, 128, 64>(wWb + (size_t)o0 * 256, 256,
                                ctx + ((size_t)b * 4096 + n0) * 256, 256, 256,
                                As, Bs, acc);
  const int lane = threadIdx.x & 63, wave = threadIdx.x >> 6;
  const int lr = lane & 15, quad = lane >> 4;
  const int wm = (wave >> 1) * 64, wn = (wave & 1) * 64;
#pragma unroll
  for (int i = 0; i < 4; ++i)
#pragma unroll
    for (int j = 0; j < 4; ++j)
#pragma unroll
      for (int r = 0; r < 4; ++r) {
        int row = wm + i * 16 + quad * 4 + r, col = wn + j * 16 + lr;
        size_t idx = ((size_t)b * 512 + o0 + row) * 4096 + n0 + col;
        out[idx] = acc[i * 4 + j][r] + bW[o0 + row] + x[idx];
      }
}

// ---------------------------------------------------------------------------
extern "C" void kernel_launch(void* const* d_in, const int* in_sizes, int n_in,
                              void* d_out, int out_size, void* d_ws, size_t ws_size,
                              hipStream_t stream)
{
  const float* x     = (const float*)d_in[0];
  const float* wq    = (const float*)d_in[1];
  // d_in[2] = bq: cancelled exactly by BN mean-subtraction
  const float* gq    = (const float*)d_in[3];
  const float* betaq = (const float*)d_in[4];
  const float* wk    = (const float*)d_in[5];
  // d_in[6] = bk: cancelled
  const float* gk    = (const float*)d_in[7];
  const float* betak = (const float*)d_in[8];
  const float* wv    = (const float*)d_in[9];
  const float* bv    = (const float*)d_in[10];
  const float* wW    = (const float*)d_in[11];
  const float* bW    = (const float*)d_in[12];
  float* out = (float*)d_out;

  // workspace layout (ws_size = 256 MiB)
  char* ws = (char*)d_ws;
  unsigned short* qt   = (unsigned short*)(ws);              //  8 MiB [4*4096,256]
  unsigned short* kt   = (unsigned short*)(ws + 8388608);    //  8 MiB
  unsigned short* v    = (unsigned short*)(ws + 16777216);   //  8 MiB [4,256,4096]
  unsigned short* ctx  = (unsigned short*)(ws + 25165824);   //  8 MiB [4*4096,256]
  unsigned short* wqk  = (unsigned short*)(ws + 33554432);   // 512 KiB [512,512]
  unsigned short* wvb  = (unsigned short*)(ws + 34078720);   // 256 KiB [256,512]
  unsigned short* wWb  = (unsigned short*)(ws + 34340864);   // 256 KiB [512,256]
  float*          stat = (float*)         (ws + 34603008);   //   4 KiB
  float*          lsum = (float*)         (ws + 34607104);   //  64 KiB [4][4096]
  float*          opart= (float*)         (ws + 35651584);   // 32 MiB [2,4,4096,256] fp32
  unsigned short* xt   = (unsigned short*)(ws + 35651584);   // 16 MiB, aliases opart
  unsigned short* zt   = (unsigned short*)(ws + 52428800);   // 16 MiB, aliases opart
                                                             // (xt dead after k_qkv,
                                                             //  zt dead after k_bnrelu,
                                                             //  both before k_att)

  (void)hipMemsetAsync(stat, 0, 69632, stream);  // stat (4K) + lsum (64K)
  k_pre   <<<3072, 256, 0, stream>>>(x, xt, wq, wk, wv, wW, wqk, wvb, wWb);
  k_qkv   <<<dim3(32, 6, 4), 256, 0, stream>>>(xt, wqk, wvb, bv, zt, v, stat);
  k_bnrelu<<<1024, 256, 0, stream>>>(zt, stat, gq, betaq, gk, betak, qt, kt);
  // grid.x = ms + 2*b (8 groups): lin%8 == group -> same-(b,ms) blocks
  // cluster on one XCD (L2 locality for the shared Q/V stream).
  k_att   <<<dim3(8, 32), 512, 0, stream>>>(qt, kt, v, opart, lsum);
  k_red   <<<4096, 256, 0, stream>>>(opart, lsum, ctx);
  k_out   <<<dim3(32, 4, 4), 256, 0, stream>>>(wWb, bW, ctx, x, out);
}